// Round 1
// baseline (1190.714 us; speedup 1.0000x reference)
//
#include <hip/hip_runtime.h>
#include <math.h>

#define N_TL 131072
#define LL 4
#define EE 64
#define HH 128
#define GRID_X 256
#define BLK 1024
#define WAVES 16
#define ITERS (N_TL / (GRID_X * WAVES))   // 32

// round fp32 -> bf16 bits (RNE)
__device__ __forceinline__ unsigned int f2bf(float x) {
  unsigned int u = __float_as_uint(x);
  return (u + 0x7fffu + ((u >> 16) & 1u)) >> 16;
}

struct alignas(16) SmemA {
  float w1[3][HH];          // lane_w1
  float b1[HH];
  float w2t[EE][132];       // w2t[e][j] = lane_w2[j][e], padded row
  float b2[EE];
  float wqt[EE][68];        // wqt[c][e] = attn_in_w[e][c]
  float wkt[EE][68];        // c+64
  float wvt[EE][68];        // c+128
  float bin[192];
  float woutt[EE][68];      // woutt[c][j] = attn_out_w[j][c]
  float bout[EE];
  float h[WAVES][HH];       // per-wave scratch (reused for mean-o)
  float emb[WAVES][LL][EE];
};

__global__ __launch_bounds__(BLK)
void lane_ctx_kernel(const float* __restrict__ queue,
                     const float* __restrict__ waiting,
                     const float* __restrict__ elapsed,
                     const float* __restrict__ lane_w1,
                     const float* __restrict__ lane_b1,
                     const float* __restrict__ lane_w2,
                     const float* __restrict__ lane_b2,
                     const float* __restrict__ attn_in_w,
                     const float* __restrict__ attn_in_b,
                     const float* __restrict__ attn_out_w,
                     const float* __restrict__ attn_out_b,
                     float* __restrict__ ctx_out) {
  __shared__ SmemA S;
  const int tid  = threadIdx.x;
  const int wv   = tid >> 6;
  const int lane = tid & 63;

  // ---- stage all weights into LDS (transposed/padded) ----
  for (int idx = tid; idx < 3 * HH; idx += BLK) S.w1[idx / HH][idx % HH] = lane_w1[idx];
  for (int idx = tid; idx < HH; idx += BLK) S.b1[idx] = lane_b1[idx];
  for (int idx = tid; idx < HH * EE; idx += BLK) { int j = idx >> 6, e = idx & 63; S.w2t[e][j] = lane_w2[idx]; }
  for (int idx = tid; idx < EE; idx += BLK) S.b2[idx] = lane_b2[idx];
  for (int idx = tid; idx < EE * 192; idx += BLK) {
    int e = idx / 192, c = idx % 192;
    float v = attn_in_w[idx];
    if (c < 64)       S.wqt[c][e] = v;
    else if (c < 128) S.wkt[c - 64][e] = v;
    else              S.wvt[c - 128][e] = v;
  }
  for (int idx = tid; idx < 192; idx += BLK) S.bin[idx] = attn_in_b[idx];
  for (int idx = tid; idx < EE * EE; idx += BLK) { int j = idx >> 6, e = idx & 63; S.woutt[e][j] = attn_out_w[idx]; }
  for (int idx = tid; idx < EE; idx += BLK) S.bout[idx] = attn_out_b[idx];
  __syncthreads();

  for (int it = 0; it < ITERS; ++it) {
    const int n = blockIdx.x * (ITERS * WAVES) + it * WAVES + wv;
    const float el = elapsed[n];

    // ---- lane MLP: h = relu(x@w1+b1); emb = relu(h@w2+b2) ----
    #pragma unroll
    for (int l = 0; l < LL; ++l) {
      const float x0 = queue[n * LL + l];
      const float x1 = waiting[n * LL + l];
      float h0 = x0 * S.w1[0][lane]      + x1 * S.w1[1][lane]      + el * S.w1[2][lane]      + S.b1[lane];
      float h1 = x0 * S.w1[0][lane + 64] + x1 * S.w1[1][lane + 64] + el * S.w1[2][lane + 64] + S.b1[lane + 64];
      S.h[wv][lane]      = fmaxf(h0, 0.f);
      S.h[wv][lane + 64] = fmaxf(h1, 0.f);
      __syncthreads();
      float acc = S.b2[lane];
      const float* wrow = S.w2t[lane];
      #pragma unroll 4
      for (int j = 0; j < HH; j += 4) {
        const float4 hv = *reinterpret_cast<const float4*>(&S.h[wv][j]);
        const float4 w4 = *reinterpret_cast<const float4*>(&wrow[j]);
        acc += hv.x * w4.x + hv.y * w4.y + hv.z * w4.z + hv.w * w4.w;
      }
      S.emb[wv][l][lane] = fmaxf(acc, 0.f);
      __syncthreads();
    }

    // ---- QKV projection: lane holds column e for q/k/v, all 4 lanes-of-TL rows ----
    float aq[LL], ak[LL], av[LL];
    #pragma unroll
    for (int l = 0; l < LL; ++l) { aq[l] = S.bin[lane]; ak[l] = S.bin[64 + lane]; av[l] = S.bin[128 + lane]; }
    {
      const float* wq  = S.wqt[lane];
      const float* wk  = S.wkt[lane];
      const float* wvp = S.wvt[lane];
      #pragma unroll 4
      for (int j = 0; j < EE; j += 4) {
        const float4 q4 = *reinterpret_cast<const float4*>(&wq[j]);
        const float4 k4 = *reinterpret_cast<const float4*>(&wk[j]);
        const float4 v4 = *reinterpret_cast<const float4*>(&wvp[j]);
        #pragma unroll
        for (int l = 0; l < LL; ++l) {
          const float4 e4 = *reinterpret_cast<const float4*>(&S.emb[wv][l][j]);
          aq[l] += e4.x * q4.x + e4.y * q4.y + e4.z * q4.z + e4.w * q4.w;
          ak[l] += e4.x * k4.x + e4.y * k4.y + e4.z * k4.z + e4.w * k4.w;
          av[l] += e4.x * v4.x + e4.y * v4.y + e4.z * v4.z + e4.w * v4.w;
        }
      }
    }

    // ---- attention: head = lane>>4, d = lane&15; 16-lane dot reductions ----
    float p[LL][LL];
    #pragma unroll
    for (int lq = 0; lq < LL; ++lq) {
      #pragma unroll
      for (int lk = 0; lk < LL; ++lk) {
        float s = aq[lq] * ak[lk];
        s += __shfl_xor(s, 1);
        s += __shfl_xor(s, 2);
        s += __shfl_xor(s, 4);
        s += __shfl_xor(s, 8);
        p[lq][lk] = s * 0.25f;   // 1/sqrt(HD=16)
      }
    }
    #pragma unroll
    for (int lq = 0; lq < LL; ++lq) {
      float m = fmaxf(fmaxf(p[lq][0], p[lq][1]), fmaxf(p[lq][2], p[lq][3]));
      float e0 = expf(p[lq][0] - m), e1 = expf(p[lq][1] - m);
      float e2 = expf(p[lq][2] - m), e3 = expf(p[lq][3] - m);
      float inv = 1.f / (e0 + e1 + e2 + e3);
      p[lq][0] = e0 * inv; p[lq][1] = e1 * inv; p[lq][2] = e2 * inv; p[lq][3] = e3 * inv;
    }
    // o[l][e] then mean over l (mean commutes with out-proj)
    float om = 0.f;
    #pragma unroll
    for (int lq = 0; lq < LL; ++lq)
      om += p[lq][0] * av[0] + p[lq][1] * av[1] + p[lq][2] * av[2] + p[lq][3] * av[3];
    om *= 0.25f;
    __syncthreads();
    S.h[wv][lane] = om;
    __syncthreads();

    // ---- out projection on the mean ----
    float ctx = S.bout[lane];
    const float* wo = S.woutt[lane];
    #pragma unroll 4
    for (int j = 0; j < EE; j += 4) {
      const float4 o4 = *reinterpret_cast<const float4*>(&S.h[wv][j]);
      const float4 w4 = *reinterpret_cast<const float4*>(&wo[j]);
      ctx += o4.x * w4.x + o4.y * w4.y + o4.z * w4.z + o4.w * w4.w;
    }
    ctx_out[(size_t)n * EE + lane] = ctx;
    __syncthreads();   // protect scratch reuse next iteration
  }
}

struct alignas(16) SmemB {
  float pw1[5][HH];
  float pb1[HH];
  float pw2t[HH][132];      // pw2t[j][i] = phase_w2[i][j]
  float pb2[HH];
  float hb1[HH];
  float hw2[HH];
  float hb2_ls[16];         // [0]=head_b2, [1]=log_std (rest pad for alignment)
  float region[4][8];
  float ph[WAVES][HH];
  float feat[WAVES][208];   // [0,64)=ctx, [64,192)=phase_emb, [192,200)=region
  unsigned int hw1u[HH][106]; // row j: packed bf16 pairs of head_w1[:,j]
};

__global__ __launch_bounds__(BLK)
void head_kernel(const float* __restrict__ phase_onehot,
                 const float* __restrict__ elapsed,
                 const int*   __restrict__ region_ids,
                 const float* __restrict__ noise,
                 const float* __restrict__ phase_w1,
                 const float* __restrict__ phase_b1,
                 const float* __restrict__ phase_w2,
                 const float* __restrict__ phase_b2,
                 const float* __restrict__ region_table,
                 const float* __restrict__ head_w1,
                 const float* __restrict__ head_b1,
                 const float* __restrict__ head_w2,
                 const float* __restrict__ head_b2,
                 const float* __restrict__ log_std,
                 const float* __restrict__ ctx_in,
                 float* __restrict__ out) {
  __shared__ SmemB S;
  const int tid  = threadIdx.x;
  const int wv   = tid >> 6;
  const int lane = tid & 63;

  for (int idx = tid; idx < 5 * HH; idx += BLK) S.pw1[idx / HH][idx % HH] = phase_w1[idx];
  for (int idx = tid; idx < HH; idx += BLK) S.pb1[idx] = phase_b1[idx];
  for (int idx = tid; idx < HH * HH; idx += BLK) { int i = idx >> 7, j = idx & 127; S.pw2t[j][i] = phase_w2[idx]; }
  for (int idx = tid; idx < HH; idx += BLK) S.pb2[idx] = phase_b2[idx];
  for (int idx = tid; idx < HH; idx += BLK) S.hb1[idx] = head_b1[idx];
  for (int idx = tid; idx < HH; idx += BLK) S.hw2[idx] = head_w2[idx];
  if (tid == 0) { S.hb2_ls[0] = head_b2[0]; S.hb2_ls[1] = log_std[0]; }
  for (int idx = tid; idx < 32; idx += BLK) S.region[idx >> 3][idx & 7] = region_table[idx];
  for (int idx = tid; idx < HH * 100; idx += BLK) {
    int j = idx & 127, w = idx >> 7;
    unsigned int lo = f2bf(head_w1[(2 * w) * HH + j]);
    unsigned int hi = f2bf(head_w1[(2 * w + 1) * HH + j]);
    S.hw1u[j][w] = lo | (hi << 16);
  }
  __syncthreads();

  for (int it = 0; it < ITERS; ++it) {
    const int n = blockIdx.x * (ITERS * WAVES) + it * WAVES + wv;
    __syncthreads();   // scratch reuse guard
    const float p0 = phase_onehot[n * 4 + 0];
    const float p1 = phase_onehot[n * 4 + 1];
    const float p2 = phase_onehot[n * 4 + 2];
    const float p3 = phase_onehot[n * 4 + 3];
    const float p4 = elapsed[n];
    float ph0 = p0 * S.pw1[0][lane]      + p1 * S.pw1[1][lane]      + p2 * S.pw1[2][lane]
              + p3 * S.pw1[3][lane]      + p4 * S.pw1[4][lane]      + S.pb1[lane];
    float ph1 = p0 * S.pw1[0][lane + 64] + p1 * S.pw1[1][lane + 64] + p2 * S.pw1[2][lane + 64]
              + p3 * S.pw1[3][lane + 64] + p4 * S.pw1[4][lane + 64] + S.pb1[lane + 64];
    S.ph[wv][lane]      = fmaxf(ph0, 0.f);
    S.ph[wv][lane + 64] = fmaxf(ph1, 0.f);
    S.feat[wv][lane] = ctx_in[(size_t)n * EE + lane];
    int rid = region_ids[n];
    rid = rid < 0 ? 0 : (rid > 3 ? 3 : rid);
    if (lane < 8) S.feat[wv][192 + lane] = S.region[rid][lane];
    __syncthreads();

    // phase layer 2
    float a0 = S.pb2[lane], a1 = S.pb2[lane + 64];
    const float* r0 = S.pw2t[lane];
    const float* r1 = S.pw2t[lane + 64];
    #pragma unroll 4
    for (int i = 0; i < HH; i += 4) {
      const float4 q4 = *reinterpret_cast<const float4*>(&S.ph[wv][i]);
      const float4 wA = *reinterpret_cast<const float4*>(&r0[i]);
      const float4 wB = *reinterpret_cast<const float4*>(&r1[i]);
      a0 += q4.x * wA.x + q4.y * wA.y + q4.z * wA.z + q4.w * wA.w;
      a1 += q4.x * wB.x + q4.y * wB.y + q4.z * wB.z + q4.w * wB.w;
    }
    S.feat[wv][64 + lane]  = fmaxf(a0, 0.f);
    S.feat[wv][128 + lane] = fmaxf(a1, 0.f);
    __syncthreads();

    // head layer 1 (bf16 weights) + layer 2 reduction
    float h0 = S.hb1[lane], h1 = S.hb1[lane + 64];
    const unsigned int* w0 = S.hw1u[lane];
    const unsigned int* w1 = S.hw1u[lane + 64];
    #pragma unroll 4
    for (int w = 0; w < 100; ++w) {
      const float2 f = *reinterpret_cast<const float2*>(&S.feat[wv][2 * w]);
      const unsigned int u0 = w0[w], u1 = w1[w];
      h0 += f.x * __uint_as_float(u0 << 16) + f.y * __uint_as_float(u0 & 0xffff0000u);
      h1 += f.x * __uint_as_float(u1 << 16) + f.y * __uint_as_float(u1 & 0xffff0000u);
    }
    h0 = fmaxf(h0, 0.f);
    h1 = fmaxf(h1, 0.f);
    float part = h0 * S.hw2[lane] + h1 * S.hw2[lane + 64];
    part += __shfl_xor(part, 1);
    part += __shfl_xor(part, 2);
    part += __shfl_xor(part, 4);
    part += __shfl_xor(part, 8);
    part += __shfl_xor(part, 16);
    part += __shfl_xor(part, 32);
    if (lane == 0) {
      const float means = part + S.hb2_ls[0];
      const float ls  = S.hb2_ls[1];
      const float std = expf(ls);
      const float nz  = noise[n];
      const float a   = means + std * nz;
      const float ac  = fminf(fmaxf(a, -1.f), 1.f);
      // (actions - means) == std*nz exactly -> log_prob independent of means
      const float lp  = -0.5f * (nz * nz + 2.f * ls + 1.8378770664093453f);
      out[n] = ac;
      out[N_TL + n] = lp;
    }
  }
}

extern "C" void kernel_launch(void* const* d_in, const int* in_sizes, int n_in,
                              void* d_out, int out_size, void* d_ws, size_t ws_size,
                              hipStream_t stream) {
  const float* queue        = (const float*)d_in[0];
  const float* waiting      = (const float*)d_in[1];
  const float* phase_onehot = (const float*)d_in[2];
  const float* elapsed      = (const float*)d_in[3];
  const int*   region_ids   = (const int*)d_in[4];
  const float* noise        = (const float*)d_in[5];
  const float* lane_w1      = (const float*)d_in[6];
  const float* lane_b1      = (const float*)d_in[7];
  const float* lane_w2      = (const float*)d_in[8];
  const float* lane_b2      = (const float*)d_in[9];
  const float* attn_in_w    = (const float*)d_in[10];
  const float* attn_in_b    = (const float*)d_in[11];
  const float* attn_out_w   = (const float*)d_in[12];
  const float* attn_out_b   = (const float*)d_in[13];
  const float* phase_w1     = (const float*)d_in[14];
  const float* phase_b1     = (const float*)d_in[15];
  const float* phase_w2     = (const float*)d_in[16];
  const float* phase_b2     = (const float*)d_in[17];
  const float* region_table = (const float*)d_in[18];
  const float* head_w1      = (const float*)d_in[19];
  const float* head_b1      = (const float*)d_in[20];
  const float* head_w2      = (const float*)d_in[21];
  const float* head_b2      = (const float*)d_in[22];
  const float* log_std      = (const float*)d_in[23];

  float* ctx_ws = (float*)d_ws;   // [N_TL, 64] fp32 = 32 MB
  float* out    = (float*)d_out;  // [2*N_TL]

  hipLaunchKernelGGL(lane_ctx_kernel, dim3(GRID_X), dim3(BLK), 0, stream,
                     queue, waiting, elapsed, lane_w1, lane_b1, lane_w2, lane_b2,
                     attn_in_w, attn_in_b, attn_out_w, attn_out_b, ctx_ws);
  hipLaunchKernelGGL(head_kernel, dim3(GRID_X), dim3(BLK), 0, stream,
                     phase_onehot, elapsed, region_ids, noise,
                     phase_w1, phase_b1, phase_w2, phase_b2, region_table,
                     head_w1, head_b1, head_w2, head_b2, log_std, ctx_ws, out);
}

// Round 2
// 405.999 us; speedup vs baseline: 2.9328x; 2.9328x over previous
//
#include <hip/hip_runtime.h>
#include <math.h>

#define N_TL 131072
#define GRID_X 256
#define BLKA 512
#define TLG 32
#define ITERA (N_TL / (GRID_X * TLG))   // 16
#define BLKB 512
#define TLB 64
#define ITERB (N_TL / (GRID_X * TLB))   // 8

typedef __attribute__((ext_vector_type(8))) short bfrag;
typedef __attribute__((ext_vector_type(4))) float f32x4;

__device__ __forceinline__ unsigned short f2bf(float x) {
  unsigned int u = __float_as_uint(x);
  return (unsigned short)((u + 0x7fffu + ((u >> 16) & 1u)) >> 16);
}
__device__ __forceinline__ float bf2f(unsigned short u) {
  return __uint_as_float(((unsigned int)u) << 16);
}
__device__ __forceinline__ f32x4 mfma16(bfrag a, bfrag b, f32x4 c) {
  return __builtin_amdgcn_mfma_f32_16x16x32_bf16(a, b, c, 0, 0, 0);
}

// Stage a global fp32 weight matrix w[K][Ncols] into LDS as B-fragments for
// mfma_f32_16x16x32_bf16. Fragment slot layout: [(ct*KK + kk)*64 + lane]*8 + j,
// holding B[k = kk*32 + quad*8 + j][n = ct*16 + (lane&15)], zero-padded for k>=K.
// Reads at MFMA time are lane-contiguous 16B -> conflict-free.
__device__ inline void stage_bfrags(unsigned short* dst, const float* __restrict__ w,
                                    int K, int KK, int CT, int Ncols, int tid, int nthr) {
  const int total = CT * KK * 64;
  for (int s = tid; s < total; s += nthr) {
    const int ct = s / (KK * 64);
    const int rem = s - ct * KK * 64;
    const int kk = rem >> 6;
    const int ln = rem & 63;
    const int kbase = kk * 32 + ((ln >> 4) & 3) * 8;
    const int n = ct * 16 + (ln & 15);
    unsigned short* o = dst + s * 8;
    #pragma unroll
    for (int j = 0; j < 8; ++j) {
      const int k = kbase + j;
      o[j] = (k < K) ? f2bf(w[k * Ncols + n]) : (unsigned short)0;
    }
  }
}

// A-fragment load from a plain [row][k] bf16 LDS array (stride in shorts, %8==0).
#define LDA(arr, stride, rt, kk) \
  (*reinterpret_cast<const bfrag*>(&(arr)[((rt) * 16 + m) * (stride) + (kk) * 32 + quad * 8]))
#define LDB(arr, KK, ct, kk) \
  (*reinterpret_cast<const bfrag*>(&(arr)[(((ct) * (KK) + (kk)) * 64 + lane) * 8]))

// ---------------------------------------------------------------- kernel A ----
struct SmemA {
  unsigned short w2f[4 * 4 * 64 * 8];     // lane_w2 [128,64] frags      16 KB
  unsigned short wqkvf[12 * 2 * 64 * 8];  // attn_in_w [64,192] frags    24 KB
  unsigned short woutf[4 * 2 * 64 * 8];   // attn_out_w [64,64] frags     8 KB
  float w1[3][128];
  float b1[128], b2[64], bin[192], bout[64];
  unsigned short act1[128 * 200];         // h (cols<128) then qkv       51.2 KB
  unsigned short emb[128 * 72];           // emb; om[32][72] overlays    18.4 KB
};

__global__ __launch_bounds__(BLKA)
void lane_ctx_mfma(const float* __restrict__ queue,
                   const float* __restrict__ waiting,
                   const float* __restrict__ elapsed,
                   const float* __restrict__ lane_w1,
                   const float* __restrict__ lane_b1,
                   const float* __restrict__ lane_w2,
                   const float* __restrict__ lane_b2,
                   const float* __restrict__ attn_in_w,
                   const float* __restrict__ attn_in_b,
                   const float* __restrict__ attn_out_w,
                   const float* __restrict__ attn_out_b,
                   float* __restrict__ ctx_out) {
  __shared__ SmemA S;
  const int tid  = threadIdx.x;
  const int wv   = tid >> 6;
  const int lane = tid & 63;
  const int m    = lane & 15;
  const int quad = lane >> 4;
  const f32x4 Z = {0.f, 0.f, 0.f, 0.f};

  stage_bfrags(S.w2f,   lane_w2,    128, 4,  4,  64, tid, BLKA);
  stage_bfrags(S.wqkvf, attn_in_w,   64, 2, 12, 192, tid, BLKA);
  stage_bfrags(S.woutf, attn_out_w,  64, 2,  4,  64, tid, BLKA);
  for (int i = tid; i < 384; i += BLKA) S.w1[i >> 7][i & 127] = lane_w1[i];
  for (int i = tid; i < 128; i += BLKA) S.b1[i] = lane_b1[i];
  for (int i = tid; i < 64;  i += BLKA) S.b2[i] = lane_b2[i];
  for (int i = tid; i < 192; i += BLKA) S.bin[i] = attn_in_b[i];
  for (int i = tid; i < 64;  i += BLKA) S.bout[i] = attn_out_b[i];
  __syncthreads();

  const int rtb = (wv >> 2) * 4;   // row-tile base: 0 or 4
  const int ctw = wv & 3;          // col-tile within wave group

  for (int it = 0; it < ITERA; ++it) {
    const int n0 = (blockIdx.x * ITERA + it) * TLG;

    // ---- layer1 (K=3) in VALU -> h bf16 into act1 cols 0..127 ----
    {
      const int r  = tid >> 2;                 // lane-row 0..127
      const int gl = n0 * 4 + r;
      const float x0 = queue[gl], x1 = waiting[gl], x2 = elapsed[n0 + (r >> 2)];
      const int c0 = (tid & 3) * 32;
      #pragma unroll 8
      for (int i = 0; i < 32; ++i) {
        const int c = c0 + i;
        const float v = x0 * S.w1[0][c] + x1 * S.w1[1][c] + x2 * S.w1[2][c] + S.b1[c];
        S.act1[r * 200 + c] = f2bf(fmaxf(v, 0.f));
      }
    }
    __syncthreads();

    // ---- layer2 MFMA: h[128,128] @ w2[128,64] -> emb (relu) ----
    {
      f32x4 a0 = Z, a1 = Z, a2 = Z, a3 = Z;
      #pragma unroll
      for (int kk = 0; kk < 4; ++kk) {
        const bfrag b = LDB(S.w2f, 4, ctw, kk);
        a0 = mfma16(LDA(S.act1, 200, rtb + 0, kk), b, a0);
        a1 = mfma16(LDA(S.act1, 200, rtb + 1, kk), b, a1);
        a2 = mfma16(LDA(S.act1, 200, rtb + 2, kk), b, a2);
        a3 = mfma16(LDA(S.act1, 200, rtb + 3, kk), b, a3);
      }
      const int col = ctw * 16 + m;
      const float bb = S.b2[col];
      const f32x4 av[4] = {a0, a1, a2, a3};
      #pragma unroll
      for (int rt4 = 0; rt4 < 4; ++rt4) {
        #pragma unroll
        for (int r = 0; r < 4; ++r) {
          const int row = (rtb + rt4) * 16 + quad * 4 + r;
          S.emb[row * 72 + col] = f2bf(fmaxf(av[rt4][r] + bb, 0.f));
        }
      }
    }
    __syncthreads();

    // ---- QKV MFMA: emb[128,64] @ attn_in_w[64,192] -> act1 (overwrites h) ----
    {
      f32x4 acc[4][3];
      #pragma unroll
      for (int i = 0; i < 4; ++i)
        #pragma unroll
        for (int j = 0; j < 3; ++j) acc[i][j] = Z;
      #pragma unroll
      for (int kk = 0; kk < 2; ++kk) {
        const bfrag b0 = LDB(S.wqkvf, 2, ctw,     kk);
        const bfrag b1 = LDB(S.wqkvf, 2, ctw + 4, kk);
        const bfrag b2 = LDB(S.wqkvf, 2, ctw + 8, kk);
        #pragma unroll
        for (int rt4 = 0; rt4 < 4; ++rt4) {
          const bfrag a = LDA(S.emb, 72, rtb + rt4, kk);
          acc[rt4][0] = mfma16(a, b0, acc[rt4][0]);
          acc[rt4][1] = mfma16(a, b1, acc[rt4][1]);
          acc[rt4][2] = mfma16(a, b2, acc[rt4][2]);
        }
      }
      #pragma unroll
      for (int cc = 0; cc < 3; ++cc) {
        const int col = (ctw + cc * 4) * 16 + m;
        const float bb = S.bin[col];
        #pragma unroll
        for (int rt4 = 0; rt4 < 4; ++rt4) {
          #pragma unroll
          for (int r = 0; r < 4; ++r) {
            const int row = (rtb + rt4) * 16 + quad * 4 + r;
            S.act1[row * 200 + col] = f2bf(acc[rt4][cc][r] + bb);
          }
        }
      }
    }
    __syncthreads();

    // ---- attention (VALU): 16 threads/TL = 4 heads x 4 queries ----
    {
      const int tl = tid >> 4;          // 0..31
      const int l16 = tid & 15;
      const int hh = l16 >> 2;
      const int lq = l16 & 3;
      float qf[16];
      {
        const unsigned short* qp = &S.act1[(tl * 4 + lq) * 200 + hh * 16];
        const bfrag q0 = *reinterpret_cast<const bfrag*>(qp);
        const bfrag q1 = *reinterpret_cast<const bfrag*>(qp + 8);
        #pragma unroll
        for (int j = 0; j < 8; ++j) {
          qf[j]     = bf2f((unsigned short)q0[j]);
          qf[8 + j] = bf2f((unsigned short)q1[j]);
        }
      }
      float sc[4];
      #pragma unroll
      for (int lk = 0; lk < 4; ++lk) {
        const unsigned short* kp = &S.act1[(tl * 4 + lk) * 200 + 64 + hh * 16];
        const bfrag k0 = *reinterpret_cast<const bfrag*>(kp);
        const bfrag k1 = *reinterpret_cast<const bfrag*>(kp + 8);
        float t = 0.f;
        #pragma unroll
        for (int j = 0; j < 8; ++j) {
          t += qf[j]     * bf2f((unsigned short)k0[j]);
          t += qf[8 + j] * bf2f((unsigned short)k1[j]);
        }
        sc[lk] = t * 0.25f;   // 1/sqrt(HD=16)
      }
      const float mx = fmaxf(fmaxf(sc[0], sc[1]), fmaxf(sc[2], sc[3]));
      const float e0 = __expf(sc[0] - mx), e1 = __expf(sc[1] - mx);
      const float e2 = __expf(sc[2] - mx), e3 = __expf(sc[3] - mx);
      const float inv = 1.f / (e0 + e1 + e2 + e3);
      const float pr[4] = {e0 * inv, e1 * inv, e2 * inv, e3 * inv};
      float o[16];
      #pragma unroll
      for (int j = 0; j < 16; ++j) o[j] = 0.f;
      #pragma unroll
      for (int lk = 0; lk < 4; ++lk) {
        const unsigned short* vp = &S.act1[(tl * 4 + lk) * 200 + 128 + hh * 16];
        const bfrag v0 = *reinterpret_cast<const bfrag*>(vp);
        const bfrag v1 = *reinterpret_cast<const bfrag*>(vp + 8);
        const float pk = pr[lk];
        #pragma unroll
        for (int j = 0; j < 8; ++j) {
          o[j]     += pk * bf2f((unsigned short)v0[j]);
          o[8 + j] += pk * bf2f((unsigned short)v1[j]);
        }
      }
      // mean over the 4 queries (lq = thread bits 0..1)
      #pragma unroll
      for (int d = 0; d < 16; ++d) {
        o[d] += __shfl_xor(o[d], 1);
        o[d] += __shfl_xor(o[d], 2);
      }
      unsigned short* om = S.emb;   // overlay: emb is dead after QKV
      #pragma unroll
      for (int d2 = 0; d2 < 4; ++d2) {
        const int d = lq * 4 + d2;
        om[tl * 72 + hh * 16 + d] = f2bf(o[d] * 0.25f);
      }
    }
    __syncthreads();

    // ---- out projection MFMA: om[32,64] @ attn_out_w[64,64] -> ctx (global) ----
    {
      const int rt = wv >> 2;   // 0..1
      f32x4 acc = Z;
      #pragma unroll
      for (int kk = 0; kk < 2; ++kk)
        acc = mfma16(LDA(S.emb, 72, rt, kk), LDB(S.woutf, 2, ctw, kk), acc);
      const int col = ctw * 16 + m;
      const float bb = S.bout[col];
      #pragma unroll
      for (int r = 0; r < 4; ++r) {
        const int n = n0 + rt * 16 + quad * 4 + r;
        ctx_out[(size_t)n * 64 + col] = acc[r] + bb;
      }
    }
    // no trailing barrier needed: next-iter act1 writes race only with
    // out-proj which reads emb/woutf; emb writes next iter are behind a barrier.
  }
}

// ---------------------------------------------------------------- kernel B ----
struct SmemB {
  unsigned short pw2f[8 * 4 * 64 * 8];    // phase_w2 [128,128] frags   32 KB
  unsigned short hw1f[8 * 7 * 64 * 8];    // head_w1 [200->224,128]     56 KB
  float pw1[5][128];
  float pb1[128], pb2[128], hb1[128], hw2[128];
  float region[4][8];
  float consts[2];                        // head_b2, log_std
  unsigned short feat[64 * 232];          // [ctx|phase_emb|region|0pad] 29.7 KB
  unsigned short ph[64 * 136];            // phase-L1 out; head-L1 out overlays
};

__global__ __launch_bounds__(BLKB)
void head_mfma(const float* __restrict__ phase_onehot,
               const float* __restrict__ elapsed,
               const int* __restrict__ region_ids,
               const float* __restrict__ noise,
               const float* __restrict__ phase_w1,
               const float* __restrict__ phase_b1,
               const float* __restrict__ phase_w2,
               const float* __restrict__ phase_b2,
               const float* __restrict__ region_table,
               const float* __restrict__ head_w1,
               const float* __restrict__ head_b1,
               const float* __restrict__ head_w2,
               const float* __restrict__ head_b2,
               const float* __restrict__ log_std,
               const float* __restrict__ ctx_in,
               float* __restrict__ out) {
  __shared__ SmemB S;
  const int tid  = threadIdx.x;
  const int wv   = tid >> 6;
  const int lane = tid & 63;
  const int m    = lane & 15;
  const int quad = lane >> 4;
  const f32x4 Z = {0.f, 0.f, 0.f, 0.f};

  stage_bfrags(S.pw2f, phase_w2, 128, 4, 8, 128, tid, BLKB);
  stage_bfrags(S.hw1f, head_w1,  200, 7, 8, 128, tid, BLKB);
  for (int i = tid; i < 640; i += BLKB) S.pw1[i >> 7][i & 127] = phase_w1[i];
  for (int i = tid; i < 128; i += BLKB) S.pb1[i] = phase_b1[i];
  for (int i = tid; i < 128; i += BLKB) S.pb2[i] = phase_b2[i];
  for (int i = tid; i < 128; i += BLKB) S.hb1[i] = head_b1[i];
  for (int i = tid; i < 128; i += BLKB) S.hw2[i] = head_w2[i];
  for (int i = tid; i < 32;  i += BLKB) S.region[i >> 3][i & 7] = region_table[i];
  if (tid == 0) { S.consts[0] = head_b2[0]; S.consts[1] = log_std[0]; }
  __syncthreads();

  const int rt0 = (wv >> 2) * 2;   // 0 or 2
  const int ctw = wv & 3;

  for (int it = 0; it < ITERB; ++it) {
    const int n0 = (blockIdx.x * ITERB + it) * TLB;

    // ---- stage feat cols 0..63 (ctx) ----
    for (int i = tid; i < 64 * 64; i += BLKB) {
      const int tl = i >> 6, c = i & 63;
      S.feat[tl * 232 + c] = f2bf(ctx_in[(size_t)(n0 + tl) * 64 + c]);
    }
    // ---- region embed cols 192..199 + zero pad 200..231 ----
    for (int i = tid; i < 64 * 40; i += BLKB) {
      const int tl = i / 40, c0 = i - tl * 40;
      float v = 0.f;
      if (c0 < 8) {
        int rid = region_ids[n0 + tl];
        rid = rid < 0 ? 0 : (rid > 3 ? 3 : rid);
        v = S.region[rid][c0];
      }
      S.feat[tl * 232 + 192 + c0] = f2bf(v);
    }
    // ---- phase L1 (K=5) in VALU -> ph ----
    {
      const int r = tid >> 3;             // TL row 0..63
      const int c0 = (tid & 7) * 16;
      const float p0 = phase_onehot[(n0 + r) * 4 + 0];
      const float p1 = phase_onehot[(n0 + r) * 4 + 1];
      const float p2 = phase_onehot[(n0 + r) * 4 + 2];
      const float p3 = phase_onehot[(n0 + r) * 4 + 3];
      const float p4 = elapsed[n0 + r];
      #pragma unroll 8
      for (int i = 0; i < 16; ++i) {
        const int c = c0 + i;
        const float v = p0 * S.pw1[0][c] + p1 * S.pw1[1][c] + p2 * S.pw1[2][c]
                      + p3 * S.pw1[3][c] + p4 * S.pw1[4][c] + S.pb1[c];
        S.ph[r * 136 + c] = f2bf(fmaxf(v, 0.f));
      }
    }
    __syncthreads();

    // ---- phase L2 MFMA: ph[64,128] @ phase_w2[128,128] -> feat cols 64..191 ----
    {
      f32x4 acc[2][2];
      acc[0][0] = Z; acc[0][1] = Z; acc[1][0] = Z; acc[1][1] = Z;
      #pragma unroll
      for (int kk = 0; kk < 4; ++kk) {
        const bfrag b0 = LDB(S.pw2f, 4, ctw,     kk);
        const bfrag b1 = LDB(S.pw2f, 4, ctw + 4, kk);
        #pragma unroll
        for (int rr = 0; rr < 2; ++rr) {
          const bfrag a = LDA(S.ph, 136, rt0 + rr, kk);
          acc[rr][0] = mfma16(a, b0, acc[rr][0]);
          acc[rr][1] = mfma16(a, b1, acc[rr][1]);
        }
      }
      #pragma unroll
      for (int cc = 0; cc < 2; ++cc) {
        const int col = (ctw + cc * 4) * 16 + m;
        const float bb = S.pb2[col];
        #pragma unroll
        for (int rr = 0; rr < 2; ++rr) {
          #pragma unroll
          for (int r = 0; r < 4; ++r) {
            const int row = (rt0 + rr) * 16 + quad * 4 + r;
            S.feat[row * 232 + 64 + col] = f2bf(fmaxf(acc[rr][cc][r] + bb, 0.f));
          }
        }
      }
    }
    __syncthreads();

    // ---- head L1 MFMA: feat[64,224] @ head_w1[224,128] -> hh (overlay ph) ----
    {
      f32x4 acc[2][2];
      acc[0][0] = Z; acc[0][1] = Z; acc[1][0] = Z; acc[1][1] = Z;
      #pragma unroll
      for (int kk = 0; kk < 7; ++kk) {
        const bfrag b0 = LDB(S.hw1f, 7, ctw,     kk);
        const bfrag b1 = LDB(S.hw1f, 7, ctw + 4, kk);
        #pragma unroll
        for (int rr = 0; rr < 2; ++rr) {
          const bfrag a = LDA(S.feat, 232, rt0 + rr, kk);
          acc[rr][0] = mfma16(a, b0, acc[rr][0]);
          acc[rr][1] = mfma16(a, b1, acc[rr][1]);
        }
      }
      #pragma unroll
      for (int cc = 0; cc < 2; ++cc) {
        const int col = (ctw + cc * 4) * 16 + m;
        const float bb = S.hb1[col];
        #pragma unroll
        for (int rr = 0; rr < 2; ++rr) {
          #pragma unroll
          for (int r = 0; r < 4; ++r) {
            const int row = (rt0 + rr) * 16 + quad * 4 + r;
            S.ph[row * 136 + col] = f2bf(fmaxf(acc[rr][cc][r] + bb, 0.f));
          }
        }
      }
    }
    __syncthreads();

    // ---- head L2 (K=128 -> 1) + gaussian: 8 threads/TL ----
    {
      const int tl = tid >> 3;   // 0..63
      const int s  = tid & 7;
      const unsigned short* hp = &S.ph[tl * 136 + s * 16];
      const bfrag h0 = *reinterpret_cast<const bfrag*>(hp);
      const bfrag h1 = *reinterpret_cast<const bfrag*>(hp + 8);
      float t = 0.f;
      #pragma unroll
      for (int j = 0; j < 8; ++j) {
        t += bf2f((unsigned short)h0[j]) * S.hw2[s * 16 + j];
        t += bf2f((unsigned short)h1[j]) * S.hw2[s * 16 + 8 + j];
      }
      t += __shfl_xor(t, 1);
      t += __shfl_xor(t, 2);
      t += __shfl_xor(t, 4);
      if (s == 0) {
        const int n = n0 + tl;
        const float means = t + S.consts[0];
        const float ls = S.consts[1];
        const float sd = __expf(ls);
        const float nz = noise[n];
        const float a = means + sd * nz;
        out[n] = fminf(fmaxf(a, -1.f), 1.f);
        // (actions - means) == sd*nz exactly -> log_prob independent of means
        out[N_TL + n] = -0.5f * (nz * nz + 2.f * ls + 1.8378770664093453f);
      }
    }
    __syncthreads();   // ph/feat rewritten next iteration
  }
}

extern "C" void kernel_launch(void* const* d_in, const int* in_sizes, int n_in,
                              void* d_out, int out_size, void* d_ws, size_t ws_size,
                              hipStream_t stream) {
  const float* queue        = (const float*)d_in[0];
  const float* waiting      = (const float*)d_in[1];
  const float* phase_onehot = (const float*)d_in[2];
  const float* elapsed      = (const float*)d_in[3];
  const int*   region_ids   = (const int*)d_in[4];
  const float* noise        = (const float*)d_in[5];
  const float* lane_w1      = (const float*)d_in[6];
  const float* lane_b1      = (const float*)d_in[7];
  const float* lane_w2      = (const float*)d_in[8];
  const float* lane_b2      = (const float*)d_in[9];
  const float* attn_in_w    = (const float*)d_in[10];
  const float* attn_in_b    = (const float*)d_in[11];
  const float* attn_out_w   = (const float*)d_in[12];
  const float* attn_out_b   = (const float*)d_in[13];
  const float* phase_w1     = (const float*)d_in[14];
  const float* phase_b1     = (const float*)d_in[15];
  const float* phase_w2     = (const float*)d_in[16];
  const float* phase_b2     = (const float*)d_in[17];
  const float* region_table = (const float*)d_in[18];
  const float* head_w1      = (const float*)d_in[19];
  const float* head_b1      = (const float*)d_in[20];
  const float* head_w2      = (const float*)d_in[21];
  const float* head_b2      = (const float*)d_in[22];
  const float* log_std      = (const float*)d_in[23];

  float* ctx_ws = (float*)d_ws;   // [N_TL, 64] fp32 = 32 MB
  float* out    = (float*)d_out;  // [2*N_TL]

  hipLaunchKernelGGL(lane_ctx_mfma, dim3(GRID_X), dim3(BLKA), 0, stream,
                     queue, waiting, elapsed, lane_w1, lane_b1, lane_w2, lane_b2,
                     attn_in_w, attn_in_b, attn_out_w, attn_out_b, ctx_ws);
  hipLaunchKernelGGL(head_mfma, dim3(GRID_X), dim3(BLKB), 0, stream,
                     phase_onehot, elapsed, region_ids, noise,
                     phase_w1, phase_b1, phase_w2, phase_b2, region_table,
                     head_w1, head_b1, head_w2, head_b2, log_std, ctx_ws, out);
}

// Round 3
// 246.113 us; speedup vs baseline: 4.8381x; 1.6496x over previous
//
#include <hip/hip_runtime.h>
#include <math.h>

#define N_TL 131072
#define GRID 1024
#define BLK 256
#define TLA 16
#define ITERA (N_TL / (GRID * TLA))   // 8
#define TLB 32
#define ITERB (N_TL / (GRID * TLB))   // 4

typedef __attribute__((ext_vector_type(8))) short bfrag;
typedef __attribute__((ext_vector_type(4))) float f32x4;

__device__ __forceinline__ unsigned short f2bf(float x) {
  unsigned int u = __float_as_uint(x);
  return (unsigned short)((u + 0x7fffu + ((u >> 16) & 1u)) >> 16);
}
__device__ __forceinline__ float bf2f(unsigned short u) {
  return __uint_as_float(((unsigned int)u) << 16);
}
__device__ __forceinline__ unsigned int pack2(float a, float b) {
  return (unsigned int)f2bf(a) | ((unsigned int)f2bf(b) << 16);
}
__device__ __forceinline__ f32x4 mfma16(bfrag a, bfrag b, f32x4 c) {
  return __builtin_amdgcn_mfma_f32_16x16x32_bf16(a, b, c, 0, 0, 0);
}

// Load a weight A-fragment (W^T) from global: A[m=col0+(lane&15)][k=k0+quad*8+j]
// = W[k][col]. 8 strided scalar loads; done once per wave at kernel start.
__device__ __forceinline__ bfrag load_wfragT(const float* __restrict__ w, int ncols,
                                             int col0, int k0, int lane) {
  const int mm = lane & 15, qq = lane >> 4;
  const float* p = w + (size_t)(k0 + qq * 8) * ncols + col0 + mm;
  bfrag f;
  #pragma unroll
  for (int j = 0; j < 8; ++j) f[j] = (short)f2bf(p[(size_t)j * ncols]);
  return f;
}

// B-operand (activations) read from row-major bf16 LDS: lane holds
// B[k=kk*32+quad*8+j][n=nt*16+(lane&15)] = act[n][k], contiguous 16B.
#define LDBACT(arr, stride, nt, kk) \
  (*reinterpret_cast<const bfrag*>(&(arr)[((nt) * 16 + m) * (stride) + (kk) * 32 + quad * 8]))

// ---------------------------------------------------------------- kernel A ----
struct alignas(16) SmemA {
  unsigned short act1[64 * 200];   // h (cols<128) then qkv (cols<192)  25.6 KB
  unsigned short emb[64 * 72];     // emb; om[16][72] overlays            9.2 KB
  float w1[3][128];
  float b1[128], b2[64], bin[192], bout[64];
};

__global__ __launch_bounds__(BLK)
void lane_ctx_mfma(const float* __restrict__ queue,
                   const float* __restrict__ waiting,
                   const float* __restrict__ elapsed,
                   const float* __restrict__ lane_w1,
                   const float* __restrict__ lane_b1,
                   const float* __restrict__ lane_w2,
                   const float* __restrict__ lane_b2,
                   const float* __restrict__ attn_in_w,
                   const float* __restrict__ attn_in_b,
                   const float* __restrict__ attn_out_w,
                   const float* __restrict__ attn_out_b,
                   unsigned short* __restrict__ ctx_out) {
  __shared__ SmemA S;
  const int tid  = threadIdx.x;
  const int wv   = tid >> 6;
  const int lane = tid & 63;
  const int m    = lane & 15;
  const int quad = lane >> 4;
  const f32x4 Z = {0.f, 0.f, 0.f, 0.f};

  // register-resident weight A-fragments (transposed)
  bfrag wL2[4], wQKV[3][2], wOUT[2];
  #pragma unroll
  for (int kk = 0; kk < 4; ++kk) wL2[kk] = load_wfragT(lane_w2, 64, wv * 16, kk * 32, lane);
  #pragma unroll
  for (int Mi = 0; Mi < 3; ++Mi)
    #pragma unroll
    for (int kk = 0; kk < 2; ++kk)
      wQKV[Mi][kk] = load_wfragT(attn_in_w, 192, (wv + Mi * 4) * 16, kk * 32, lane);
  #pragma unroll
  for (int kk = 0; kk < 2; ++kk) wOUT[kk] = load_wfragT(attn_out_w, 64, wv * 16, kk * 32, lane);

  for (int i = tid; i < 384; i += BLK) S.w1[i >> 7][i & 127] = lane_w1[i];
  for (int i = tid; i < 128; i += BLK) S.b1[i] = lane_b1[i];
  for (int i = tid; i < 64;  i += BLK) S.b2[i] = lane_b2[i];
  for (int i = tid; i < 192; i += BLK) S.bin[i] = attn_in_b[i];
  for (int i = tid; i < 64;  i += BLK) S.bout[i] = attn_out_b[i];
  __syncthreads();

  for (int it = 0; it < ITERA; ++it) {
    const int n0 = (blockIdx.x * ITERA + it) * TLA;

    // ---- layer1 (K=3) VALU -> h bf16, packed b128 writes ----
    {
      const int r  = tid >> 2;                 // lane-row 0..63
      const int gl = n0 * 4 + r;
      const float x0 = queue[gl], x1 = waiting[gl], x2 = elapsed[n0 + (r >> 2)];
      const int c0 = (tid & 3) * 32;
      unsigned int pk[16];
      #pragma unroll
      for (int i = 0; i < 16; ++i) {
        const int c = c0 + 2 * i;
        const float v0 = fmaxf(x0 * S.w1[0][c]     + x1 * S.w1[1][c]     + x2 * S.w1[2][c]     + S.b1[c],     0.f);
        const float v1 = fmaxf(x0 * S.w1[0][c + 1] + x1 * S.w1[1][c + 1] + x2 * S.w1[2][c + 1] + S.b1[c + 1], 0.f);
        pk[i] = pack2(v0, v1);
      }
      uint4* dst = reinterpret_cast<uint4*>(&S.act1[r * 200 + c0]);
      dst[0] = make_uint4(pk[0], pk[1], pk[2], pk[3]);
      dst[1] = make_uint4(pk[4], pk[5], pk[6], pk[7]);
      dst[2] = make_uint4(pk[8], pk[9], pk[10], pk[11]);
      dst[3] = make_uint4(pk[12], pk[13], pk[14], pk[15]);
    }
    __syncthreads();

    // ---- layer2: emb^T = w2^T @ h : D[outcol][row], packed b64 epilogue ----
    {
      f32x4 acc[4] = {Z, Z, Z, Z};
      #pragma unroll
      for (int Nt = 0; Nt < 4; ++Nt)
        #pragma unroll
        for (int kk = 0; kk < 4; ++kk)
          acc[Nt] = mfma16(wL2[kk], LDBACT(S.act1, 200, Nt, kk), acc[Nt]);
      const int oc0 = wv * 16 + quad * 4;
      const float bb0 = S.b2[oc0], bb1 = S.b2[oc0 + 1], bb2 = S.b2[oc0 + 2], bb3 = S.b2[oc0 + 3];
      #pragma unroll
      for (int Nt = 0; Nt < 4; ++Nt) {
        const int row = Nt * 16 + m;
        uint2 u;
        u.x = pack2(fmaxf(acc[Nt][0] + bb0, 0.f), fmaxf(acc[Nt][1] + bb1, 0.f));
        u.y = pack2(fmaxf(acc[Nt][2] + bb2, 0.f), fmaxf(acc[Nt][3] + bb3, 0.f));
        *reinterpret_cast<uint2*>(&S.emb[row * 72 + oc0]) = u;
      }
    }
    __syncthreads();

    // ---- QKV: qkv^T = Win^T @ emb ----
    {
      f32x4 acc[3][4];
      #pragma unroll
      for (int Mi = 0; Mi < 3; ++Mi)
        #pragma unroll
        for (int Nt = 0; Nt < 4; ++Nt) acc[Mi][Nt] = Z;
      #pragma unroll
      for (int Nt = 0; Nt < 4; ++Nt) {
        const bfrag e0 = LDBACT(S.emb, 72, Nt, 0);
        const bfrag e1 = LDBACT(S.emb, 72, Nt, 1);
        #pragma unroll
        for (int Mi = 0; Mi < 3; ++Mi) {
          acc[Mi][Nt] = mfma16(wQKV[Mi][0], e0, acc[Mi][Nt]);
          acc[Mi][Nt] = mfma16(wQKV[Mi][1], e1, acc[Mi][Nt]);
        }
      }
      #pragma unroll
      for (int Mi = 0; Mi < 3; ++Mi) {
        const int oc0 = (wv + Mi * 4) * 16 + quad * 4;
        const float bb0 = S.bin[oc0], bb1 = S.bin[oc0 + 1], bb2 = S.bin[oc0 + 2], bb3 = S.bin[oc0 + 3];
        #pragma unroll
        for (int Nt = 0; Nt < 4; ++Nt) {
          const int row = Nt * 16 + m;
          uint2 u;
          u.x = pack2(acc[Mi][Nt][0] + bb0, acc[Mi][Nt][1] + bb1);
          u.y = pack2(acc[Mi][Nt][2] + bb2, acc[Mi][Nt][3] + bb3);
          *reinterpret_cast<uint2*>(&S.act1[row * 200 + oc0]) = u;
        }
      }
    }
    __syncthreads();

    // ---- attention (VALU): 16 threads/TL = 4 heads x 4 queries ----
    {
      const int tl = tid >> 4;          // 0..15
      const int l16 = tid & 15;
      const int hh = l16 >> 2;
      const int lq = l16 & 3;
      float qf[16];
      {
        const unsigned short* qp = &S.act1[(tl * 4 + lq) * 200 + hh * 16];
        const bfrag q0 = *reinterpret_cast<const bfrag*>(qp);
        const bfrag q1 = *reinterpret_cast<const bfrag*>(qp + 8);
        #pragma unroll
        for (int j = 0; j < 8; ++j) {
          qf[j]     = bf2f((unsigned short)q0[j]);
          qf[8 + j] = bf2f((unsigned short)q1[j]);
        }
      }
      float sc[4];
      #pragma unroll
      for (int lk = 0; lk < 4; ++lk) {
        const unsigned short* kp = &S.act1[(tl * 4 + lk) * 200 + 64 + hh * 16];
        const bfrag k0 = *reinterpret_cast<const bfrag*>(kp);
        const bfrag k1 = *reinterpret_cast<const bfrag*>(kp + 8);
        float t = 0.f;
        #pragma unroll
        for (int j = 0; j < 8; ++j) {
          t += qf[j]     * bf2f((unsigned short)k0[j]);
          t += qf[8 + j] * bf2f((unsigned short)k1[j]);
        }
        sc[lk] = t * 0.25f;   // 1/sqrt(HD=16)
      }
      const float mx = fmaxf(fmaxf(sc[0], sc[1]), fmaxf(sc[2], sc[3]));
      const float e0 = __expf(sc[0] - mx), e1 = __expf(sc[1] - mx);
      const float e2 = __expf(sc[2] - mx), e3 = __expf(sc[3] - mx);
      const float inv = 1.f / (e0 + e1 + e2 + e3);
      const float pr[4] = {e0 * inv, e1 * inv, e2 * inv, e3 * inv};
      float o[16];
      #pragma unroll
      for (int j = 0; j < 16; ++j) o[j] = 0.f;
      #pragma unroll
      for (int lk = 0; lk < 4; ++lk) {
        const unsigned short* vp = &S.act1[(tl * 4 + lk) * 200 + 128 + hh * 16];
        const bfrag v0 = *reinterpret_cast<const bfrag*>(vp);
        const bfrag v1 = *reinterpret_cast<const bfrag*>(vp + 8);
        const float pk = pr[lk];
        #pragma unroll
        for (int j = 0; j < 8; ++j) {
          o[j]     += pk * bf2f((unsigned short)v0[j]);
          o[8 + j] += pk * bf2f((unsigned short)v1[j]);
        }
      }
      // mean over the 4 queries (lq = lane bits 0..1)
      #pragma unroll
      for (int d = 0; d < 16; ++d) {
        o[d] += __shfl_xor(o[d], 1);
        o[d] += __shfl_xor(o[d], 2);
      }
      // om overlays emb rows 0..15 (emb consumed by QKV, behind barrier)
      uint2 u;
      u.x = pack2(o[lq * 4 + 0] * 0.25f, o[lq * 4 + 1] * 0.25f);
      u.y = pack2(o[lq * 4 + 2] * 0.25f, o[lq * 4 + 3] * 0.25f);
      *reinterpret_cast<uint2*>(&S.emb[tl * 72 + hh * 16 + lq * 4]) = u;
    }
    __syncthreads();

    // ---- out-proj: ctx^T = Wout^T @ om ; lane m = TL, 4 outcols packed ----
    {
      f32x4 acc = Z;
      acc = mfma16(wOUT[0], LDBACT(S.emb, 72, 0, 0), acc);
      acc = mfma16(wOUT[1], LDBACT(S.emb, 72, 0, 1), acc);
      const int oc0 = wv * 16 + quad * 4;
      uint2 u;
      u.x = pack2(acc[0] + S.bout[oc0],     acc[1] + S.bout[oc0 + 1]);
      u.y = pack2(acc[2] + S.bout[oc0 + 2], acc[3] + S.bout[oc0 + 3]);
      *reinterpret_cast<uint2*>(&ctx_out[(size_t)(n0 + m) * 64 + oc0]) = u;
    }
    // next-iter layer1 writes act1 only after the post-layer1 barrier; safe.
  }
}

// ---------------------------------------------------------------- kernel B ----
struct alignas(16) SmemB {
  unsigned short feat[32 * 200];   // [ctx(64) | phase_emb(128)]        12.8 KB
  unsigned short ph[32 * 136];     // phase-L1 out; head-L1 out overlays 8.7 KB
  float pw1[5][128];
  float pb1[128], pb2[128];
  float rbias[4][128];             // head_b1 + region[g] @ head_w1[192:200,:]
  float hw2[128];
  float consts[2];
  int ridx[32];
};

__global__ __launch_bounds__(BLK)
void head_mfma(const float* __restrict__ phase_onehot,
               const float* __restrict__ elapsed,
               const int* __restrict__ region_ids,
               const float* __restrict__ noise,
               const float* __restrict__ phase_w1,
               const float* __restrict__ phase_b1,
               const float* __restrict__ phase_w2,
               const float* __restrict__ phase_b2,
               const float* __restrict__ region_table,
               const float* __restrict__ head_w1,
               const float* __restrict__ head_b1,
               const float* __restrict__ head_w2,
               const float* __restrict__ head_b2,
               const float* __restrict__ log_std,
               const unsigned short* __restrict__ ctx_in,
               float* __restrict__ out) {
  __shared__ SmemB S;
  const int tid  = threadIdx.x;
  const int wv   = tid >> 6;
  const int lane = tid & 63;
  const int m    = lane & 15;
  const int quad = lane >> 4;
  const f32x4 Z = {0.f, 0.f, 0.f, 0.f};

  // register-resident weight A-fragments (transposed); wave owns outcol tiles {wv, wv+4}
  bfrag wP2[2][4], wH1[2][6];
  #pragma unroll
  for (int Mi = 0; Mi < 2; ++Mi) {
    #pragma unroll
    for (int kk = 0; kk < 4; ++kk)
      wP2[Mi][kk] = load_wfragT(phase_w2, 128, (wv + Mi * 4) * 16, kk * 32, lane);
    #pragma unroll
    for (int kk = 0; kk < 6; ++kk)
      wH1[Mi][kk] = load_wfragT(head_w1, 128, (wv + Mi * 4) * 16, kk * 32, lane);
  }

  for (int i = tid; i < 640; i += BLK) S.pw1[i >> 7][i & 127] = phase_w1[i];
  for (int i = tid; i < 128; i += BLK) S.pb1[i] = phase_b1[i];
  for (int i = tid; i < 128; i += BLK) S.pb2[i] = phase_b2[i];
  for (int i = tid; i < 128; i += BLK) S.hw2[i] = head_w2[i];
  // fold region embedding + head_b1 into per-region bias
  for (int i = tid; i < 512; i += BLK) {
    const int g = i >> 7, c = i & 127;
    float acc = head_b1[c];
    #pragma unroll
    for (int j = 0; j < 8; ++j) acc += region_table[g * 8 + j] * head_w1[(192 + j) * 128 + c];
    S.rbias[g][c] = acc;
  }
  if (tid == 0) { S.consts[0] = head_b2[0]; S.consts[1] = log_std[0]; }
  __syncthreads();

  for (int it = 0; it < ITERB; ++it) {
    const int n0 = (blockIdx.x * ITERB + it) * TLB;

    // ---- stage ctx (bf16 b128 copy), region ids, phase L1 ----
    {
      const int row = tid >> 3;
      const int c8 = (tid & 7) * 8;
      *reinterpret_cast<uint4*>(&S.feat[row * 200 + c8]) =
          *reinterpret_cast<const uint4*>(&ctx_in[(size_t)(n0 + row) * 64 + c8]);
      if (tid < 32) {
        int r = region_ids[n0 + tid];
        S.ridx[tid] = r < 0 ? 0 : (r > 3 ? 3 : r);
      }
      const float p0 = phase_onehot[(n0 + row) * 4 + 0];
      const float p1 = phase_onehot[(n0 + row) * 4 + 1];
      const float p2 = phase_onehot[(n0 + row) * 4 + 2];
      const float p3 = phase_onehot[(n0 + row) * 4 + 3];
      const float p4 = elapsed[n0 + row];
      const int c0 = (tid & 7) * 16;
      unsigned int pk[8];
      #pragma unroll
      for (int i = 0; i < 8; ++i) {
        const int c = c0 + 2 * i;
        const float v0 = fmaxf(p0 * S.pw1[0][c]     + p1 * S.pw1[1][c]     + p2 * S.pw1[2][c]
                             + p3 * S.pw1[3][c]     + p4 * S.pw1[4][c]     + S.pb1[c],     0.f);
        const float v1 = fmaxf(p0 * S.pw1[0][c + 1] + p1 * S.pw1[1][c + 1] + p2 * S.pw1[2][c + 1]
                             + p3 * S.pw1[3][c + 1] + p4 * S.pw1[4][c + 1] + S.pb1[c + 1], 0.f);
        pk[i] = pack2(v0, v1);
      }
      uint4* dst = reinterpret_cast<uint4*>(&S.ph[row * 136 + c0]);
      dst[0] = make_uint4(pk[0], pk[1], pk[2], pk[3]);
      dst[1] = make_uint4(pk[4], pk[5], pk[6], pk[7]);
    }
    __syncthreads();

    // ---- phase L2: pe^T = pw2^T @ ph -> feat cols 64..191 ----
    {
      f32x4 acc[2][2];
      acc[0][0] = Z; acc[0][1] = Z; acc[1][0] = Z; acc[1][1] = Z;
      #pragma unroll
      for (int Nt = 0; Nt < 2; ++Nt)
        #pragma unroll
        for (int kk = 0; kk < 4; ++kk) {
          const bfrag b = LDBACT(S.ph, 136, Nt, kk);
          acc[0][Nt] = mfma16(wP2[0][kk], b, acc[0][Nt]);
          acc[1][Nt] = mfma16(wP2[1][kk], b, acc[1][Nt]);
        }
      #pragma unroll
      for (int Mi = 0; Mi < 2; ++Mi) {
        const int oc0 = (wv + Mi * 4) * 16 + quad * 4;
        const float bb0 = S.pb2[oc0], bb1 = S.pb2[oc0 + 1], bb2 = S.pb2[oc0 + 2], bb3 = S.pb2[oc0 + 3];
        #pragma unroll
        for (int Nt = 0; Nt < 2; ++Nt) {
          const int row = Nt * 16 + m;
          uint2 u;
          u.x = pack2(fmaxf(acc[Mi][Nt][0] + bb0, 0.f), fmaxf(acc[Mi][Nt][1] + bb1, 0.f));
          u.y = pack2(fmaxf(acc[Mi][Nt][2] + bb2, 0.f), fmaxf(acc[Mi][Nt][3] + bb3, 0.f));
          *reinterpret_cast<uint2*>(&S.feat[row * 200 + 64 + oc0]) = u;
        }
      }
    }
    __syncthreads();

    // ---- head L1 (K=192): hh^T = hw1^T @ feat, per-region bias ----
    {
      f32x4 acc[2][2];
      acc[0][0] = Z; acc[0][1] = Z; acc[1][0] = Z; acc[1][1] = Z;
      #pragma unroll
      for (int Nt = 0; Nt < 2; ++Nt)
        #pragma unroll
        for (int kk = 0; kk < 6; ++kk) {
          const bfrag b = LDBACT(S.feat, 200, Nt, kk);
          acc[0][Nt] = mfma16(wH1[0][kk], b, acc[0][Nt]);
          acc[1][Nt] = mfma16(wH1[1][kk], b, acc[1][Nt]);
        }
      #pragma unroll
      for (int Mi = 0; Mi < 2; ++Mi) {
        const int oc0 = (wv + Mi * 4) * 16 + quad * 4;
        #pragma unroll
        for (int Nt = 0; Nt < 2; ++Nt) {
          const int row = Nt * 16 + m;
          const f32x4 bb = *reinterpret_cast<const f32x4*>(&S.rbias[S.ridx[row]][oc0]);
          uint2 u;
          u.x = pack2(fmaxf(acc[Mi][Nt][0] + bb[0], 0.f), fmaxf(acc[Mi][Nt][1] + bb[1], 0.f));
          u.y = pack2(fmaxf(acc[Mi][Nt][2] + bb[2], 0.f), fmaxf(acc[Mi][Nt][3] + bb[3], 0.f));
          *reinterpret_cast<uint2*>(&S.ph[row * 136 + oc0]) = u;   // hh overlay
        }
      }
    }
    __syncthreads();

    // ---- head L2 (128->1) + gaussian: 8 threads/TL ----
    {
      const int tl = tid >> 3;   // 0..31
      const int s  = tid & 7;
      const unsigned short* hp = &S.ph[tl * 136 + s * 16];
      const bfrag h0 = *reinterpret_cast<const bfrag*>(hp);
      const bfrag h1 = *reinterpret_cast<const bfrag*>(hp + 8);
      float t = 0.f;
      #pragma unroll
      for (int j = 0; j < 8; ++j) {
        t += bf2f((unsigned short)h0[j]) * S.hw2[s * 16 + j];
        t += bf2f((unsigned short)h1[j]) * S.hw2[s * 16 + 8 + j];
      }
      t += __shfl_xor(t, 1);
      t += __shfl_xor(t, 2);
      t += __shfl_xor(t, 4);
      if (s == 0) {
        const int n = n0 + tl;
        const float means = t + S.consts[0];
        const float ls = S.consts[1];
        const float sd = __expf(ls);
        const float nz = noise[n];
        const float a = means + sd * nz;
        out[n] = fminf(fmaxf(a, -1.f), 1.f);
        // (actions - means) == sd*nz exactly -> log_prob independent of means
        out[N_TL + n] = -0.5f * (nz * nz + 2.f * ls + 1.8378770664093453f);
      }
    }
    __syncthreads();   // ph/feat rewritten next iteration
  }
}

extern "C" void kernel_launch(void* const* d_in, const int* in_sizes, int n_in,
                              void* d_out, int out_size, void* d_ws, size_t ws_size,
                              hipStream_t stream) {
  const float* queue        = (const float*)d_in[0];
  const float* waiting      = (const float*)d_in[1];
  const float* phase_onehot = (const float*)d_in[2];
  const float* elapsed      = (const float*)d_in[3];
  const int*   region_ids   = (const int*)d_in[4];
  const float* noise        = (const float*)d_in[5];
  const float* lane_w1      = (const float*)d_in[6];
  const float* lane_b1      = (const float*)d_in[7];
  const float* lane_w2      = (const float*)d_in[8];
  const float* lane_b2      = (const float*)d_in[9];
  const float* attn_in_w    = (const float*)d_in[10];
  const float* attn_in_b    = (const float*)d_in[11];
  const float* attn_out_w   = (const float*)d_in[12];
  const float* attn_out_b   = (const float*)d_in[13];
  const float* phase_w1     = (const float*)d_in[14];
  const float* phase_b1     = (const float*)d_in[15];
  const float* phase_w2     = (const float*)d_in[16];
  const float* phase_b2     = (const float*)d_in[17];
  const float* region_table = (const float*)d_in[18];
  const float* head_w1      = (const float*)d_in[19];
  const float* head_b1      = (const float*)d_in[20];
  const float* head_w2      = (const float*)d_in[21];
  const float* head_b2      = (const float*)d_in[22];
  const float* log_std      = (const float*)d_in[23];

  unsigned short* ctx_ws = (unsigned short*)d_ws;   // [N_TL, 64] bf16 = 16 MB
  float* out = (float*)d_out;                       // [2*N_TL]

  hipLaunchKernelGGL(lane_ctx_mfma, dim3(GRID), dim3(BLK), 0, stream,
                     queue, waiting, elapsed, lane_w1, lane_b1, lane_w2, lane_b2,
                     attn_in_w, attn_in_b, attn_out_w, attn_out_b, ctx_ws);
  hipLaunchKernelGGL(head_mfma, dim3(GRID), dim3(BLK), 0, stream,
                     phase_onehot, elapsed, region_ids, noise,
                     phase_w1, phase_b1, phase_w2, phase_b2, region_table,
                     head_w1, head_b1, head_w2, head_b2, log_std, ctx_ws, out);
}

// Round 4
// 217.195 us; speedup vs baseline: 5.4822x; 1.1331x over previous
//
#include <hip/hip_runtime.h>
#include <math.h>

#define N_TL 131072
#define GRID 1024
#define BLK 256
#define TLA 16
#define ITERA 8
#define TLB 32
#define ITERB 4

typedef __attribute__((ext_vector_type(8))) short bfrag;
typedef __attribute__((ext_vector_type(4))) float f32x4;

// RNE bf16 (weights, staged once)
__device__ __forceinline__ unsigned short f2bf_rne(float x) {
  unsigned int u = __float_as_uint(x);
  return (unsigned short)((u + 0x7fffu + ((u >> 16) & 1u)) >> 16);
}
// cheap round-half-up pack of 2 floats -> bf16x2 (activations)
__device__ __forceinline__ unsigned int pack2(float a, float b) {
  return ((__float_as_uint(a) + 0x8000u) >> 16) |
         ((__float_as_uint(b) + 0x8000u) & 0xffff0000u);
}
__device__ __forceinline__ f32x4 mfma16(bfrag a, bfrag b, f32x4 c) {
  return __builtin_amdgcn_mfma_f32_16x16x32_bf16(a, b, c, 0, 0, 0);
}
__device__ __forceinline__ float dot4(float4 a, float4 b) {
  return a.x * b.x + a.y * b.y + a.z * b.z + a.w * b.w;
}

// Weight A-fragment (W^T): A[m=col0+(lane&15)][k=k0+quad*8+j] = W[k][col]*scale, 0 for k>=K.
__device__ __forceinline__ bfrag load_wfragT(const float* __restrict__ w, int ncols,
                                             int col0, int k0, int lane, int K, float scale) {
  const int mm = lane & 15, qq = lane >> 4;
  bfrag f;
  #pragma unroll
  for (int j = 0; j < 8; ++j) {
    const int k = k0 + qq * 8 + j;
    const float v = (k < K) ? w[(size_t)k * ncols + col0 + mm] * scale : 0.f;
    f[j] = (short)f2bf_rne(v);
  }
  return f;
}

// B-operand (activations) from row-major bf16 LDS
#define LDBACT(arr, stride, nt, kk) \
  (*reinterpret_cast<const bfrag*>(&(arr)[((nt) * 16 + m) * (stride) + (kk) * 32 + quad * 8]))

// ---------------------------------------------------------------- kernel A ----
struct alignas(16) SmemA {
  union {
    float qkvf[64 * 196];          // qkv f32 (50.2 KB)
    unsigned short h[64 * 136];    // layer1 out bf16 (17.4 KB), dead before qkv write
  };
  unsigned short emb[64 * 72];     // emb; om[16][264] overlays (9.2 KB)
  unsigned short xbuf[64 * 32];    // layer1 input, K-padded (4 KB)
  float b1[128], b2[64], bin[192], bout[64];
};

__global__ __launch_bounds__(BLK)
void lane_ctx_mfma(const float* __restrict__ queue,
                   const float* __restrict__ waiting,
                   const float* __restrict__ elapsed,
                   const float* __restrict__ lane_w1,
                   const float* __restrict__ lane_b1,
                   const float* __restrict__ lane_w2,
                   const float* __restrict__ lane_b2,
                   const float* __restrict__ attn_in_w,
                   const float* __restrict__ attn_in_b,
                   const float* __restrict__ attn_out_w,
                   const float* __restrict__ attn_out_b,
                   unsigned short* __restrict__ ctx_out) {
  __shared__ SmemA S;
  const int tid  = threadIdx.x;
  const int wv   = tid >> 6;
  const int lane = tid & 63;
  const int m    = lane & 15;
  const int quad = lane >> 4;
  const f32x4 Z = {0.f, 0.f, 0.f, 0.f};

  // register-resident weight fragments
  bfrag wL1[2], wL2[4], wQKV[3][2], wOUT[8];
  #pragma unroll
  for (int Mi = 0; Mi < 2; ++Mi)
    wL1[Mi] = load_wfragT(lane_w1, 128, (wv * 2 + Mi) * 16, 0, lane, 3, 1.f);
  #pragma unroll
  for (int kk = 0; kk < 4; ++kk)
    wL2[kk] = load_wfragT(lane_w2, 64, wv * 16, kk * 32, lane, 128, 1.f);
  #pragma unroll
  for (int Mi = 0; Mi < 3; ++Mi)
    #pragma unroll
    for (int kk = 0; kk < 2; ++kk)
      wQKV[Mi][kk] = load_wfragT(attn_in_w, 192, (wv + Mi * 4) * 16, kk * 32, lane, 64,
                                 Mi == 0 ? 0.25f : 1.f);   // fold 1/sqrt(HD) into Q
  // out-proj folded with query-mean: K=256 (lq,e), W'[k][c] = Wout[k&63][c]*0.25
  #pragma unroll
  for (int kk = 0; kk < 8; ++kk) {
    bfrag f;
    #pragma unroll
    for (int j = 0; j < 8; ++j) {
      const int k = kk * 32 + quad * 8 + j;
      f[j] = (short)f2bf_rne(attn_out_w[(size_t)(k & 63) * 64 + wv * 16 + m] * 0.25f);
    }
    wOUT[kk] = f;
  }

  for (int i = tid; i < 128; i += BLK) S.b1[i] = lane_b1[i];
  for (int i = tid; i < 64;  i += BLK) S.b2[i] = lane_b2[i];
  for (int i = tid; i < 192; i += BLK) S.bin[i] = attn_in_b[i] * ((i < 64) ? 0.25f : 1.f);
  for (int i = tid; i < 64;  i += BLK) S.bout[i] = attn_out_b[i];
  // stage x for iteration 0
  {
    const int n0 = blockIdx.x * ITERA * TLA;
    const int r = tid >> 2, seg = tid & 3;
    uint4 z = {0, 0, 0, 0};
    if (seg == 0) {
      const int gl = n0 * 4 + r;
      z.x = pack2(queue[gl], waiting[gl]);
      z.y = pack2(elapsed[n0 + (r >> 2)], 0.f);
    }
    *reinterpret_cast<uint4*>(&S.xbuf[r * 32 + seg * 8]) = z;
  }
  __syncthreads();

  for (int it = 0; it < ITERA; ++it) {
    const int n0 = (blockIdx.x * ITERA + it) * TLA;

    // ---- layer1 MFMA (K=32 zero-padded): h^T = w1^T @ x ----
    {
      f32x4 acc[2][4];
      #pragma unroll
      for (int Mi = 0; Mi < 2; ++Mi)
        #pragma unroll
        for (int Nt = 0; Nt < 4; ++Nt) acc[Mi][Nt] = Z;
      #pragma unroll
      for (int Nt = 0; Nt < 4; ++Nt) {
        const bfrag b = LDBACT(S.xbuf, 32, Nt, 0);
        acc[0][Nt] = mfma16(wL1[0], b, acc[0][Nt]);
        acc[1][Nt] = mfma16(wL1[1], b, acc[1][Nt]);
      }
      #pragma unroll
      for (int Mi = 0; Mi < 2; ++Mi) {
        const int oc0 = (wv * 2 + Mi) * 16 + quad * 4;
        const f32x4 bb = *reinterpret_cast<const f32x4*>(&S.b1[oc0]);
        #pragma unroll
        for (int Nt = 0; Nt < 4; ++Nt) {
          const int row = Nt * 16 + m;
          uint2 u;
          u.x = pack2(fmaxf(acc[Mi][Nt][0] + bb[0], 0.f), fmaxf(acc[Mi][Nt][1] + bb[1], 0.f));
          u.y = pack2(fmaxf(acc[Mi][Nt][2] + bb[2], 0.f), fmaxf(acc[Mi][Nt][3] + bb[3], 0.f));
          *reinterpret_cast<uint2*>(&S.h[row * 136 + oc0]) = u;
        }
      }
    }
    __syncthreads();

    // ---- layer2: emb^T = w2^T @ h ----
    {
      f32x4 acc[4] = {Z, Z, Z, Z};
      #pragma unroll
      for (int Nt = 0; Nt < 4; ++Nt)
        #pragma unroll
        for (int kk = 0; kk < 4; ++kk)
          acc[Nt] = mfma16(wL2[kk], LDBACT(S.h, 136, Nt, kk), acc[Nt]);
      const int oc0 = wv * 16 + quad * 4;
      const f32x4 bb = *reinterpret_cast<const f32x4*>(&S.b2[oc0]);
      #pragma unroll
      for (int Nt = 0; Nt < 4; ++Nt) {
        const int row = Nt * 16 + m;
        uint2 u;
        u.x = pack2(fmaxf(acc[Nt][0] + bb[0], 0.f), fmaxf(acc[Nt][1] + bb[1], 0.f));
        u.y = pack2(fmaxf(acc[Nt][2] + bb[2], 0.f), fmaxf(acc[Nt][3] + bb[3], 0.f));
        *reinterpret_cast<uint2*>(&S.emb[row * 72 + oc0]) = u;
      }
    }
    __syncthreads();

    // ---- QKV: qkv^T = Win^T @ emb, f32 output; prefetch next x ----
    {
      f32x4 acc[3][4];
      #pragma unroll
      for (int Mi = 0; Mi < 3; ++Mi)
        #pragma unroll
        for (int Nt = 0; Nt < 4; ++Nt) acc[Mi][Nt] = Z;
      #pragma unroll
      for (int Nt = 0; Nt < 4; ++Nt) {
        const bfrag e0 = LDBACT(S.emb, 72, Nt, 0);
        const bfrag e1 = LDBACT(S.emb, 72, Nt, 1);
        #pragma unroll
        for (int Mi = 0; Mi < 3; ++Mi) {
          acc[Mi][Nt] = mfma16(wQKV[Mi][0], e0, acc[Mi][Nt]);
          acc[Mi][Nt] = mfma16(wQKV[Mi][1], e1, acc[Mi][Nt]);
        }
      }
      #pragma unroll
      for (int Mi = 0; Mi < 3; ++Mi) {
        const int oc0 = (wv + Mi * 4) * 16 + quad * 4;
        const f32x4 bb = *reinterpret_cast<const f32x4*>(&S.bin[oc0]);
        #pragma unroll
        for (int Nt = 0; Nt < 4; ++Nt) {
          const int row = Nt * 16 + m;
          const f32x4 o = acc[Mi][Nt] + bb;
          *reinterpret_cast<f32x4*>(&S.qkvf[row * 196 + oc0]) = o;
        }
      }
      // prefetch next iteration's x into xbuf (wraps on last iter; harmless)
      const int nn0 = (blockIdx.x * ITERA + ((it + 1) & (ITERA - 1))) * TLA;
      const int r = tid >> 2, seg = tid & 3;
      uint4 z = {0, 0, 0, 0};
      if (seg == 0) {
        const int gl = nn0 * 4 + r;
        z.x = pack2(queue[gl], waiting[gl]);
        z.y = pack2(elapsed[nn0 + (r >> 2)], 0.f);
      }
      *reinterpret_cast<uint4*>(&S.xbuf[r * 32 + seg * 8]) = z;
    }
    __syncthreads();

    // ---- attention (f32 VALU): 16 threads/TL = 4 heads x 4 queries ----
    {
      const int tl = tid >> 4, l16 = tid & 15;
      const int hh = l16 >> 2, lq = l16 & 3;
      const float* qb = &S.qkvf[(tl * 4 + lq) * 196 + hh * 16];
      const float4 q0 = *reinterpret_cast<const float4*>(qb);
      const float4 q1 = *reinterpret_cast<const float4*>(qb + 4);
      const float4 q2 = *reinterpret_cast<const float4*>(qb + 8);
      const float4 q3 = *reinterpret_cast<const float4*>(qb + 12);
      float sc[4];
      #pragma unroll
      for (int lk = 0; lk < 4; ++lk) {
        const float* kb = &S.qkvf[(tl * 4 + lk) * 196 + 64 + hh * 16];
        sc[lk] = dot4(q0, *reinterpret_cast<const float4*>(kb))
               + dot4(q1, *reinterpret_cast<const float4*>(kb + 4))
               + dot4(q2, *reinterpret_cast<const float4*>(kb + 8))
               + dot4(q3, *reinterpret_cast<const float4*>(kb + 12));
      }
      const float mx = fmaxf(fmaxf(sc[0], sc[1]), fmaxf(sc[2], sc[3]));
      const float e0 = __expf(sc[0] - mx), e1 = __expf(sc[1] - mx);
      const float e2 = __expf(sc[2] - mx), e3 = __expf(sc[3] - mx);
      const float inv = 1.f / (e0 + e1 + e2 + e3);
      const float pr[4] = {e0 * inv, e1 * inv, e2 * inv, e3 * inv};
      float4 o0 = {0,0,0,0}, o1 = {0,0,0,0}, o2 = {0,0,0,0}, o3 = {0,0,0,0};
      #pragma unroll
      for (int lk = 0; lk < 4; ++lk) {
        const float* vb = &S.qkvf[(tl * 4 + lk) * 196 + 128 + hh * 16];
        const float4 v0 = *reinterpret_cast<const float4*>(vb);
        const float4 v1 = *reinterpret_cast<const float4*>(vb + 4);
        const float4 v2 = *reinterpret_cast<const float4*>(vb + 8);
        const float4 v3 = *reinterpret_cast<const float4*>(vb + 12);
        const float p = pr[lk];
        o0.x += p * v0.x; o0.y += p * v0.y; o0.z += p * v0.z; o0.w += p * v0.w;
        o1.x += p * v1.x; o1.y += p * v1.y; o1.z += p * v1.z; o1.w += p * v1.w;
        o2.x += p * v2.x; o2.y += p * v2.y; o2.z += p * v2.z; o2.w += p * v2.w;
        o3.x += p * v3.x; o3.y += p * v3.y; o3.z += p * v3.z; o3.w += p * v3.w;
      }
      // write raw o (pre-mean) to om[tl][lq*64 + hh*16 + d]; mean folded into wOUT
      unsigned short* om = S.emb;
      const int base = tl * 264 + lq * 64 + hh * 16;
      *reinterpret_cast<uint4*>(&om[base]) =
          make_uint4(pack2(o0.x, o0.y), pack2(o0.z, o0.w), pack2(o1.x, o1.y), pack2(o1.z, o1.w));
      *reinterpret_cast<uint4*>(&om[base + 8]) =
          make_uint4(pack2(o2.x, o2.y), pack2(o2.z, o2.w), pack2(o3.x, o3.y), pack2(o3.z, o3.w));
    }
    __syncthreads();

    // ---- out-proj (K=256, mean folded): ctx^T = W'^T @ om ----
    {
      f32x4 acc = Z;
      #pragma unroll
      for (int kk = 0; kk < 8; ++kk)
        acc = mfma16(wOUT[kk], LDBACT(S.emb, 264, 0, kk), acc);
      const int oc0 = wv * 16 + quad * 4;
      uint2 u;
      u.x = pack2(acc[0] + S.bout[oc0],     acc[1] + S.bout[oc0 + 1]);
      u.y = pack2(acc[2] + S.bout[oc0 + 2], acc[3] + S.bout[oc0 + 3]);
      *reinterpret_cast<uint2*>(&ctx_out[(size_t)(n0 + m) * 64 + oc0]) = u;
    }
    // layer1(i+1) writes S.h only after next barrier; om readers done at loop top
  }
}

// ---------------------------------------------------------------- kernel B ----
struct alignas(16) SmemB {
  unsigned short feat[32 * 200];   // [ctx(64) | phase_emb(128)] 12.8 KB
  unsigned short ph[32 * 136];     // pL1 out; head-L1 out overlays 8.7 KB
  unsigned short xb[32 * 32];      // phase-L1 input, K-padded 2 KB
  float pb1[128], pb2[128];
  float rbias[4][128];             // head_b1 + region[g] @ head_w1[192:200,:]
  float hw2[128];
  float consts[2];
  int ridx[32];
};

__global__ __launch_bounds__(BLK)
void head_mfma(const float* __restrict__ phase_onehot,
               const float* __restrict__ elapsed,
               const int* __restrict__ region_ids,
               const float* __restrict__ noise,
               const float* __restrict__ phase_w1,
               const float* __restrict__ phase_b1,
               const float* __restrict__ phase_w2,
               const float* __restrict__ phase_b2,
               const float* __restrict__ region_table,
               const float* __restrict__ head_w1,
               const float* __restrict__ head_b1,
               const float* __restrict__ head_w2,
               const float* __restrict__ head_b2,
               const float* __restrict__ log_std,
               const unsigned short* __restrict__ ctx_in,
               float* __restrict__ out) {
  __shared__ SmemB S;
  const int tid  = threadIdx.x;
  const int wv   = tid >> 6;
  const int lane = tid & 63;
  const int m    = lane & 15;
  const int quad = lane >> 4;
  const f32x4 Z = {0.f, 0.f, 0.f, 0.f};

  bfrag wP1[2], wP2[2][4], wH1[2][6];
  #pragma unroll
  for (int Mi = 0; Mi < 2; ++Mi) {
    wP1[Mi] = load_wfragT(phase_w1, 128, (wv * 2 + Mi) * 16, 0, lane, 5, 1.f);
    #pragma unroll
    for (int kk = 0; kk < 4; ++kk)
      wP2[Mi][kk] = load_wfragT(phase_w2, 128, (wv + Mi * 4) * 16, kk * 32, lane, 128, 1.f);
    #pragma unroll
    for (int kk = 0; kk < 6; ++kk)
      wH1[Mi][kk] = load_wfragT(head_w1, 128, (wv + Mi * 4) * 16, kk * 32, lane, 192, 1.f);
  }

  for (int i = tid; i < 128; i += BLK) S.pb1[i] = phase_b1[i];
  for (int i = tid; i < 128; i += BLK) S.pb2[i] = phase_b2[i];
  for (int i = tid; i < 128; i += BLK) S.hw2[i] = head_w2[i];
  for (int i = tid; i < 512; i += BLK) {
    const int g = i >> 7, c = i & 127;
    float acc = head_b1[c];
    #pragma unroll
    for (int j = 0; j < 8; ++j) acc += region_table[g * 8 + j] * head_w1[(192 + j) * 128 + c];
    S.rbias[g][c] = acc;
  }
  if (tid == 0) { S.consts[0] = head_b2[0]; S.consts[1] = log_std[0]; }
  // stage iteration 0 inputs
  {
    const int n0 = blockIdx.x * ITERB * TLB;
    const int row = tid >> 3, c8 = (tid & 7) * 8;
    *reinterpret_cast<uint4*>(&S.feat[row * 200 + c8]) =
        *reinterpret_cast<const uint4*>(&ctx_in[(size_t)(n0 + row) * 64 + c8]);
    if (tid < 128) {
      const int r = tid >> 2, seg = tid & 3;
      uint4 z = {0, 0, 0, 0};
      if (seg == 0) {
        const float4 p = *reinterpret_cast<const float4*>(&phase_onehot[(n0 + r) * 4]);
        z.x = pack2(p.x, p.y);
        z.y = pack2(p.z, p.w);
        z.z = pack2(elapsed[n0 + r], 0.f);
      }
      *reinterpret_cast<uint4*>(&S.xb[r * 32 + seg * 8]) = z;
    }
    if (tid < 32) {
      int r = region_ids[n0 + tid];
      S.ridx[tid] = r < 0 ? 0 : (r > 3 ? 3 : r);
    }
  }
  __syncthreads();

  for (int it = 0; it < ITERB; ++it) {
    const int n0 = (blockIdx.x * ITERB + it) * TLB;

    // ---- phase L1 MFMA (K=32 zero-padded) ----
    {
      f32x4 acc[2][2];
      acc[0][0] = Z; acc[0][1] = Z; acc[1][0] = Z; acc[1][1] = Z;
      #pragma unroll
      for (int Nt = 0; Nt < 2; ++Nt) {
        const bfrag b = LDBACT(S.xb, 32, Nt, 0);
        acc[0][Nt] = mfma16(wP1[0], b, acc[0][Nt]);
        acc[1][Nt] = mfma16(wP1[1], b, acc[1][Nt]);
      }
      #pragma unroll
      for (int Mi = 0; Mi < 2; ++Mi) {
        const int oc0 = (wv * 2 + Mi) * 16 + quad * 4;
        const f32x4 bb = *reinterpret_cast<const f32x4*>(&S.pb1[oc0]);
        #pragma unroll
        for (int Nt = 0; Nt < 2; ++Nt) {
          const int row = Nt * 16 + m;
          uint2 u;
          u.x = pack2(fmaxf(acc[Mi][Nt][0] + bb[0], 0.f), fmaxf(acc[Mi][Nt][1] + bb[1], 0.f));
          u.y = pack2(fmaxf(acc[Mi][Nt][2] + bb[2], 0.f), fmaxf(acc[Mi][Nt][3] + bb[3], 0.f));
          *reinterpret_cast<uint2*>(&S.ph[row * 136 + oc0]) = u;
        }
      }
    }
    __syncthreads();

    // ---- phase L2: pe^T = pw2^T @ ph -> feat cols 64..191 ----
    {
      f32x4 acc[2][2];
      acc[0][0] = Z; acc[0][1] = Z; acc[1][0] = Z; acc[1][1] = Z;
      #pragma unroll
      for (int Nt = 0; Nt < 2; ++Nt)
        #pragma unroll
        for (int kk = 0; kk < 4; ++kk) {
          const bfrag b = LDBACT(S.ph, 136, Nt, kk);
          acc[0][Nt] = mfma16(wP2[0][kk], b, acc[0][Nt]);
          acc[1][Nt] = mfma16(wP2[1][kk], b, acc[1][Nt]);
        }
      #pragma unroll
      for (int Mi = 0; Mi < 2; ++Mi) {
        const int oc0 = (wv + Mi * 4) * 16 + quad * 4;
        const f32x4 bb = *reinterpret_cast<const f32x4*>(&S.pb2[oc0]);
        #pragma unroll
        for (int Nt = 0; Nt < 2; ++Nt) {
          const int row = Nt * 16 + m;
          uint2 u;
          u.x = pack2(fmaxf(acc[Mi][Nt][0] + bb[0], 0.f), fmaxf(acc[Mi][Nt][1] + bb[1], 0.f));
          u.y = pack2(fmaxf(acc[Mi][Nt][2] + bb[2], 0.f), fmaxf(acc[Mi][Nt][3] + bb[3], 0.f));
          *reinterpret_cast<uint2*>(&S.feat[row * 200 + 64 + oc0]) = u;
        }
      }
    }
    __syncthreads();

    // ---- head L1 (K=192): hh^T = hw1^T @ feat ----
    {
      f32x4 acc[2][2];
      acc[0][0] = Z; acc[0][1] = Z; acc[1][0] = Z; acc[1][1] = Z;
      #pragma unroll
      for (int Nt = 0; Nt < 2; ++Nt)
        #pragma unroll
        for (int kk = 0; kk < 6; ++kk) {
          const bfrag b = LDBACT(S.feat, 200, Nt, kk);
          acc[0][Nt] = mfma16(wH1[0][kk], b, acc[0][Nt]);
          acc[1][Nt] = mfma16(wH1[1][kk], b, acc[1][Nt]);
        }
      #pragma unroll
      for (int Mi = 0; Mi < 2; ++Mi) {
        const int oc0 = (wv + Mi * 4) * 16 + quad * 4;
        #pragma unroll
        for (int Nt = 0; Nt < 2; ++Nt) {
          const int row = Nt * 16 + m;
          const f32x4 bb = *reinterpret_cast<const f32x4*>(&S.rbias[S.ridx[row]][oc0]);
          uint2 u;
          u.x = pack2(fmaxf(acc[Mi][Nt][0] + bb[0], 0.f), fmaxf(acc[Mi][Nt][1] + bb[1], 0.f));
          u.y = pack2(fmaxf(acc[Mi][Nt][2] + bb[2], 0.f), fmaxf(acc[Mi][Nt][3] + bb[3], 0.f));
          *reinterpret_cast<uint2*>(&S.ph[row * 136 + oc0]) = u;   // hh overlay
        }
      }
    }
    __syncthreads();

    // ---- head L2 (128->1) + gaussian; prefetch next iteration's inputs ----
    {
      const int tl = tid >> 3, s = tid & 7;
      const unsigned short* hp = &S.ph[tl * 136 + s * 16];
      const bfrag h0 = *reinterpret_cast<const bfrag*>(hp);
      const bfrag h1 = *reinterpret_cast<const bfrag*>(hp + 8);
      float t = 0.f;
      #pragma unroll
      for (int j = 0; j < 8; ++j) {
        t += __uint_as_float(((unsigned int)(unsigned short)h0[j]) << 16) * S.hw2[s * 16 + j];
        t += __uint_as_float(((unsigned int)(unsigned short)h1[j]) << 16) * S.hw2[s * 16 + 8 + j];
      }
      t += __shfl_xor(t, 1);
      t += __shfl_xor(t, 2);
      t += __shfl_xor(t, 4);
      if (s == 0) {
        const int n = n0 + tl;
        const float means = t + S.consts[0];
        const float ls = S.consts[1];
        const float nz = noise[n];
        const float a = means + __expf(ls) * nz;
        out[n] = fminf(fmaxf(a, -1.f), 1.f);
        out[N_TL + n] = -0.5f * (nz * nz + 2.f * ls + 1.8378770664093453f);
      }
      // prefetch next iter (wraps on last; harmless)
      const int nn0 = (blockIdx.x * ITERB + ((it + 1) & (ITERB - 1))) * TLB;
      const int row = tid >> 3, c8 = (tid & 7) * 8;
      *reinterpret_cast<uint4*>(&S.feat[row * 200 + c8]) =
          *reinterpret_cast<const uint4*>(&ctx_in[(size_t)(nn0 + row) * 64 + c8]);
      if (tid < 128) {
        const int r = tid >> 2, seg = tid & 3;
        uint4 z = {0, 0, 0, 0};
        if (seg == 0) {
          const float4 p = *reinterpret_cast<const float4*>(&phase_onehot[(nn0 + r) * 4]);
          z.x = pack2(p.x, p.y);
          z.y = pack2(p.z, p.w);
          z.z = pack2(elapsed[nn0 + r], 0.f);
        }
        *reinterpret_cast<uint4*>(&S.xb[r * 32 + seg * 8]) = z;
      }
      if (tid < 32) {
        int r = region_ids[nn0 + tid];
        S.ridx[tid] = r < 0 ? 0 : (r > 3 ? 3 : r);
      }
    }
    __syncthreads();
  }
}

extern "C" void kernel_launch(void* const* d_in, const int* in_sizes, int n_in,
                              void* d_out, int out_size, void* d_ws, size_t ws_size,
                              hipStream_t stream) {
  const float* queue        = (const float*)d_in[0];
  const float* waiting      = (const float*)d_in[1];
  const float* phase_onehot = (const float*)d_in[2];
  const float* elapsed      = (const float*)d_in[3];
  const int*   region_ids   = (const int*)d_in[4];
  const float* noise        = (const float*)d_in[5];
  const float* lane_w1      = (const float*)d_in[6];
  const float* lane_b1      = (const float*)d_in[7];
  const float* lane_w2      = (const float*)d_in[8];
  const float* lane_b2      = (const float*)d_in[9];
  const float* attn_in_w    = (const float*)d_in[10];
  const float* attn_in_b    = (const float*)d_in[11];
  const float* attn_out_w   = (const float*)d_in[12];
  const float* attn_out_b   = (const float*)d_in[13];
  const float* phase_w1     = (const float*)d_in[14];
  const float* phase_b1     = (const float*)d_in[15];
  const float* phase_w2     = (const float*)d_in[16];
  const float* phase_b2     = (const float*)d_in[17];
  const float* region_table = (const float*)d_in[18];
  const float* head_w1      = (const float*)d_in[19];
  const float* head_b1      = (const float*)d_in[20];
  const float* head_w2      = (const float*)d_in[21];
  const float* head_b2      = (const float*)d_in[22];
  const float* log_std      = (const float*)d_in[23];

  unsigned short* ctx_ws = (unsigned short*)d_ws;   // [N_TL, 64] bf16
  float* out = (float*)d_out;

  hipLaunchKernelGGL(lane_ctx_mfma, dim3(GRID), dim3(BLK), 0, stream,
                     queue, waiting, elapsed, lane_w1, lane_b1, lane_w2, lane_b2,
                     attn_in_w, attn_in_b, attn_out_w, attn_out_b, ctx_ws);
  hipLaunchKernelGGL(head_mfma, dim3(GRID), dim3(BLK), 0, stream,
                     phase_onehot, elapsed, region_ids, noise,
                     phase_w1, phase_b1, phase_w2, phase_b2, region_table,
                     head_w1, head_b1, head_w2, head_b2, log_std, ctx_ws, out);
}

// Round 5
// 209.321 us; speedup vs baseline: 5.6885x; 1.0376x over previous
//
#include <hip/hip_runtime.h>
#include <math.h>

#define N_TL 131072
#define GRID 1024
#define BLKA 256
#define TLA 16
#define ITERA 8
#define BLKB 512
#define TLB 64
#define ITERB 2

typedef __attribute__((ext_vector_type(8))) short bfrag;
typedef __attribute__((ext_vector_type(4))) float f32x4;

// RNE bf16 (weights, staged once)
__device__ __forceinline__ unsigned short f2bf_rne(float x) {
  unsigned int u = __float_as_uint(x);
  return (unsigned short)((u + 0x7fffu + ((u >> 16) & 1u)) >> 16);
}
// cheap round-half-up pack of 2 floats -> bf16x2 (activations)
__device__ __forceinline__ unsigned int pack2(float a, float b) {
  return ((__float_as_uint(a) + 0x8000u) >> 16) |
         ((__float_as_uint(b) + 0x8000u) & 0xffff0000u);
}
__device__ __forceinline__ f32x4 mfma16(bfrag a, bfrag b, f32x4 c) {
  return __builtin_amdgcn_mfma_f32_16x16x32_bf16(a, b, c, 0, 0, 0);
}
__device__ __forceinline__ float dot4(float4 a, float4 b) {
  return a.x * b.x + a.y * b.y + a.z * b.z + a.w * b.w;
}

// Weight A-fragment (W^T): A[m=col0+(lane&15)][k=k0+quad*8+j] = W[k][col]*scale, 0 for k>=K.
__device__ __forceinline__ bfrag load_wfragT(const float* __restrict__ w, int ncols,
                                             int col0, int k0, int lane, int K, float scale) {
  const int mm = lane & 15, qq = lane >> 4;
  bfrag f;
  #pragma unroll
  for (int j = 0; j < 8; ++j) {
    const int k = k0 + qq * 8 + j;
    const float v = (k < K) ? w[(size_t)k * ncols + col0 + mm] * scale : 0.f;
    f[j] = (short)f2bf_rne(v);
  }
  return f;
}

// B-operand (activations) from row-major bf16 LDS
#define LDBACT(arr, stride, nt, kk) \
  (*reinterpret_cast<const bfrag*>(&(arr)[((nt) * 16 + m) * (stride) + (kk) * 32 + quad * 8]))

// ---------------------------------------------------------------- kernel A ----
struct alignas(16) SmemA {
  union {
    float qkvf[64 * 196];          // qkv f32 (50.2 KB)
    unsigned short h[64 * 136];    // layer1 out bf16 (17.4 KB), dead before qkv write
  };
  unsigned short emb[64 * 72];     // emb; om[16][264] overlays (9.2 KB)
  unsigned short xbuf[64 * 32];    // layer1 input, K-padded (4 KB)
  float b1[128], b2[64], bin[192], bout[64];
};

__global__ __launch_bounds__(BLKA)
void lane_ctx_mfma(const float* __restrict__ queue,
                   const float* __restrict__ waiting,
                   const float* __restrict__ elapsed,
                   const float* __restrict__ lane_w1,
                   const float* __restrict__ lane_b1,
                   const float* __restrict__ lane_w2,
                   const float* __restrict__ lane_b2,
                   const float* __restrict__ attn_in_w,
                   const float* __restrict__ attn_in_b,
                   const float* __restrict__ attn_out_w,
                   const float* __restrict__ attn_out_b,
                   unsigned short* __restrict__ ctx_out) {
  __shared__ SmemA S;
  const int tid  = threadIdx.x;
  const int wv   = tid >> 6;
  const int lane = tid & 63;
  const int m    = lane & 15;
  const int quad = lane >> 4;
  const f32x4 Z = {0.f, 0.f, 0.f, 0.f};

  // register-resident weight fragments
  bfrag wL1[2], wL2[4], wQKV[3][2], wOUT[8];
  #pragma unroll
  for (int Mi = 0; Mi < 2; ++Mi)
    wL1[Mi] = load_wfragT(lane_w1, 128, (wv * 2 + Mi) * 16, 0, lane, 3, 1.f);
  #pragma unroll
  for (int kk = 0; kk < 4; ++kk)
    wL2[kk] = load_wfragT(lane_w2, 64, wv * 16, kk * 32, lane, 128, 1.f);
  #pragma unroll
  for (int Mi = 0; Mi < 3; ++Mi)
    #pragma unroll
    for (int kk = 0; kk < 2; ++kk)
      wQKV[Mi][kk] = load_wfragT(attn_in_w, 192, (wv + Mi * 4) * 16, kk * 32, lane, 64,
                                 Mi == 0 ? 0.25f : 1.f);   // fold 1/sqrt(HD) into Q
  // out-proj folded with query-mean: K=256 (lq,e), W'[k][c] = Wout[k&63][c]*0.25
  #pragma unroll
  for (int kk = 0; kk < 8; ++kk) {
    bfrag f;
    #pragma unroll
    for (int j = 0; j < 8; ++j) {
      const int k = kk * 32 + quad * 8 + j;
      f[j] = (short)f2bf_rne(attn_out_w[(size_t)(k & 63) * 64 + wv * 16 + m] * 0.25f);
    }
    wOUT[kk] = f;
  }

  for (int i = tid; i < 128; i += BLKA) S.b1[i] = lane_b1[i];
  for (int i = tid; i < 64;  i += BLKA) S.b2[i] = lane_b2[i];
  for (int i = tid; i < 192; i += BLKA) S.bin[i] = attn_in_b[i] * ((i < 64) ? 0.25f : 1.f);
  for (int i = tid; i < 64;  i += BLKA) S.bout[i] = attn_out_b[i];
  // stage x for iteration 0
  {
    const int n0 = blockIdx.x * ITERA * TLA;
    const int r = tid >> 2, seg = tid & 3;
    uint4 z = {0, 0, 0, 0};
    if (seg == 0) {
      const int gl = n0 * 4 + r;
      z.x = pack2(queue[gl], waiting[gl]);
      z.y = pack2(elapsed[n0 + (r >> 2)], 0.f);
    }
    *reinterpret_cast<uint4*>(&S.xbuf[r * 32 + seg * 8]) = z;
  }
  __syncthreads();

  for (int it = 0; it < ITERA; ++it) {
    const int n0 = (blockIdx.x * ITERA + it) * TLA;

    // ---- layer1 MFMA (K=32 zero-padded): h^T = w1^T @ x ----
    {
      f32x4 acc[2][4];
      #pragma unroll
      for (int Mi = 0; Mi < 2; ++Mi)
        #pragma unroll
        for (int Nt = 0; Nt < 4; ++Nt) acc[Mi][Nt] = Z;
      #pragma unroll
      for (int Nt = 0; Nt < 4; ++Nt) {
        const bfrag b = LDBACT(S.xbuf, 32, Nt, 0);
        acc[0][Nt] = mfma16(wL1[0], b, acc[0][Nt]);
        acc[1][Nt] = mfma16(wL1[1], b, acc[1][Nt]);
      }
      #pragma unroll
      for (int Mi = 0; Mi < 2; ++Mi) {
        const int oc0 = (wv * 2 + Mi) * 16 + quad * 4;
        const f32x4 bb = *reinterpret_cast<const f32x4*>(&S.b1[oc0]);
        #pragma unroll
        for (int Nt = 0; Nt < 4; ++Nt) {
          const int row = Nt * 16 + m;
          uint2 u;
          u.x = pack2(fmaxf(acc[Mi][Nt][0] + bb[0], 0.f), fmaxf(acc[Mi][Nt][1] + bb[1], 0.f));
          u.y = pack2(fmaxf(acc[Mi][Nt][2] + bb[2], 0.f), fmaxf(acc[Mi][Nt][3] + bb[3], 0.f));
          *reinterpret_cast<uint2*>(&S.h[row * 136 + oc0]) = u;
        }
      }
    }
    __syncthreads();

    // ---- layer2: emb^T = w2^T @ h ----
    {
      f32x4 acc[4] = {Z, Z, Z, Z};
      #pragma unroll
      for (int Nt = 0; Nt < 4; ++Nt)
        #pragma unroll
        for (int kk = 0; kk < 4; ++kk)
          acc[Nt] = mfma16(wL2[kk], LDBACT(S.h, 136, Nt, kk), acc[Nt]);
      const int oc0 = wv * 16 + quad * 4;
      const f32x4 bb = *reinterpret_cast<const f32x4*>(&S.b2[oc0]);
      #pragma unroll
      for (int Nt = 0; Nt < 4; ++Nt) {
        const int row = Nt * 16 + m;
        uint2 u;
        u.x = pack2(fmaxf(acc[Nt][0] + bb[0], 0.f), fmaxf(acc[Nt][1] + bb[1], 0.f));
        u.y = pack2(fmaxf(acc[Nt][2] + bb[2], 0.f), fmaxf(acc[Nt][3] + bb[3], 0.f));
        *reinterpret_cast<uint2*>(&S.emb[row * 72 + oc0]) = u;
      }
    }
    __syncthreads();

    // ---- QKV: qkv^T = Win^T @ emb, f32 output; prefetch next x ----
    {
      f32x4 acc[3][4];
      #pragma unroll
      for (int Mi = 0; Mi < 3; ++Mi)
        #pragma unroll
        for (int Nt = 0; Nt < 4; ++Nt) acc[Mi][Nt] = Z;
      #pragma unroll
      for (int Nt = 0; Nt < 4; ++Nt) {
        const bfrag e0 = LDBACT(S.emb, 72, Nt, 0);
        const bfrag e1 = LDBACT(S.emb, 72, Nt, 1);
        #pragma unroll
        for (int Mi = 0; Mi < 3; ++Mi) {
          acc[Mi][Nt] = mfma16(wQKV[Mi][0], e0, acc[Mi][Nt]);
          acc[Mi][Nt] = mfma16(wQKV[Mi][1], e1, acc[Mi][Nt]);
        }
      }
      #pragma unroll
      for (int Mi = 0; Mi < 3; ++Mi) {
        const int oc0 = (wv + Mi * 4) * 16 + quad * 4;
        const f32x4 bb = *reinterpret_cast<const f32x4*>(&S.bin[oc0]);
        #pragma unroll
        for (int Nt = 0; Nt < 4; ++Nt) {
          const int row = Nt * 16 + m;
          const f32x4 o = acc[Mi][Nt] + bb;
          *reinterpret_cast<f32x4*>(&S.qkvf[row * 196 + oc0]) = o;
        }
      }
      // prefetch next iteration's x into xbuf (wraps on last iter; harmless)
      const int nn0 = (blockIdx.x * ITERA + ((it + 1) & (ITERA - 1))) * TLA;
      const int r = tid >> 2, seg = tid & 3;
      uint4 z = {0, 0, 0, 0};
      if (seg == 0) {
        const int gl = nn0 * 4 + r;
        z.x = pack2(queue[gl], waiting[gl]);
        z.y = pack2(elapsed[nn0 + (r >> 2)], 0.f);
      }
      *reinterpret_cast<uint4*>(&S.xbuf[r * 32 + seg * 8]) = z;
    }
    __syncthreads();

    // ---- attention (f32 VALU): 16 threads/TL = 4 heads x 4 queries ----
    {
      const int tl = tid >> 4, l16 = tid & 15;
      const int hh = l16 >> 2, lq = l16 & 3;
      const float* qb = &S.qkvf[(tl * 4 + lq) * 196 + hh * 16];
      const float4 q0 = *reinterpret_cast<const float4*>(qb);
      const float4 q1 = *reinterpret_cast<const float4*>(qb + 4);
      const float4 q2 = *reinterpret_cast<const float4*>(qb + 8);
      const float4 q3 = *reinterpret_cast<const float4*>(qb + 12);
      float sc[4];
      #pragma unroll
      for (int lk = 0; lk < 4; ++lk) {
        const float* kb = &S.qkvf[(tl * 4 + lk) * 196 + 64 + hh * 16];
        sc[lk] = dot4(q0, *reinterpret_cast<const float4*>(kb))
               + dot4(q1, *reinterpret_cast<const float4*>(kb + 4))
               + dot4(q2, *reinterpret_cast<const float4*>(kb + 8))
               + dot4(q3, *reinterpret_cast<const float4*>(kb + 12));
      }
      const float mx = fmaxf(fmaxf(sc[0], sc[1]), fmaxf(sc[2], sc[3]));
      const float e0 = __expf(sc[0] - mx), e1 = __expf(sc[1] - mx);
      const float e2 = __expf(sc[2] - mx), e3 = __expf(sc[3] - mx);
      const float inv = 1.f / (e0 + e1 + e2 + e3);
      const float pr[4] = {e0 * inv, e1 * inv, e2 * inv, e3 * inv};
      float4 o0 = {0,0,0,0}, o1 = {0,0,0,0}, o2 = {0,0,0,0}, o3 = {0,0,0,0};
      #pragma unroll
      for (int lk = 0; lk < 4; ++lk) {
        const float* vb = &S.qkvf[(tl * 4 + lk) * 196 + 128 + hh * 16];
        const float4 v0 = *reinterpret_cast<const float4*>(vb);
        const float4 v1 = *reinterpret_cast<const float4*>(vb + 4);
        const float4 v2 = *reinterpret_cast<const float4*>(vb + 8);
        const float4 v3 = *reinterpret_cast<const float4*>(vb + 12);
        const float p = pr[lk];
        o0.x += p * v0.x; o0.y += p * v0.y; o0.z += p * v0.z; o0.w += p * v0.w;
        o1.x += p * v1.x; o1.y += p * v1.y; o1.z += p * v1.z; o1.w += p * v1.w;
        o2.x += p * v2.x; o2.y += p * v2.y; o2.z += p * v2.z; o2.w += p * v2.w;
        o3.x += p * v3.x; o3.y += p * v3.y; o3.z += p * v3.z; o3.w += p * v3.w;
      }
      // mean folded into wOUT; write raw o to om[tl][lq*64 + hh*16 + d]
      #pragma unroll
      for (int d = 0; d < 1; ++d) {}   // (keep structure)
      unsigned short* om = S.emb;
      const int base = tl * 264 + lq * 64 + hh * 16;
      *reinterpret_cast<uint4*>(&om[base]) =
          make_uint4(pack2(o0.x, o0.y), pack2(o0.z, o0.w), pack2(o1.x, o1.y), pack2(o1.z, o1.w));
      *reinterpret_cast<uint4*>(&om[base + 8]) =
          make_uint4(pack2(o2.x, o2.y), pack2(o2.z, o2.w), pack2(o3.x, o3.y), pack2(o3.z, o3.w));
    }
    __syncthreads();

    // ---- out-proj (K=256, mean folded): ctx^T = W'^T @ om ----
    {
      f32x4 acc = Z;
      #pragma unroll
      for (int kk = 0; kk < 8; ++kk)
        acc = mfma16(wOUT[kk], LDBACT(S.emb, 264, 0, kk), acc);
      const int oc0 = wv * 16 + quad * 4;
      uint2 u;
      u.x = pack2(acc[0] + S.bout[oc0],     acc[1] + S.bout[oc0 + 1]);
      u.y = pack2(acc[2] + S.bout[oc0 + 2], acc[3] + S.bout[oc0 + 3]);
      *reinterpret_cast<uint2*>(&ctx_out[(size_t)(n0 + m) * 64 + oc0]) = u;
    }
  }
}

// ---------------------------------------------------------------- kernel B ----
// BLK=512: 8 waves, each owns ONE 16-col output tile (128 cols total).
// 64 TLs/iter (Nt=4), ITERB=2 -> 8 barrier phases/block instead of 20.
struct alignas(16) SmemB {
  unsigned short feat[64 * 200];   // [ctx(64) | phase_emb(128)] 25.6 KB
  unsigned short ph[64 * 136];     // pL1 out; head-L1 out overlays 17.4 KB
  unsigned short xb[64 * 32];      // phase-L1 input, K-padded 4 KB
  float pb1[128], pb2[128];
  float rbias[4][128];             // head_b1 + region[g] @ head_w1[192:200,:]
  float hw2[128];
  float consts[2];
  int ridx[64];
};

__global__ __launch_bounds__(BLKB)
void head_mfma(const float* __restrict__ phase_onehot,
               const float* __restrict__ elapsed,
               const int* __restrict__ region_ids,
               const float* __restrict__ noise,
               const float* __restrict__ phase_w1,
               const float* __restrict__ phase_b1,
               const float* __restrict__ phase_w2,
               const float* __restrict__ phase_b2,
               const float* __restrict__ region_table,
               const float* __restrict__ head_w1,
               const float* __restrict__ head_b1,
               const float* __restrict__ head_w2,
               const float* __restrict__ head_b2,
               const float* __restrict__ log_std,
               const unsigned short* __restrict__ ctx_in,
               float* __restrict__ out) {
  __shared__ SmemB S;
  const int tid  = threadIdx.x;
  const int wv   = tid >> 6;          // 0..7 -> output col tile
  const int lane = tid & 63;
  const int m    = lane & 15;
  const int quad = lane >> 4;
  const f32x4 Z = {0.f, 0.f, 0.f, 0.f};

  // 11 register frags per wave (vs 22 before)
  bfrag wP1, wP2[4], wH1[6];
  wP1 = load_wfragT(phase_w1, 128, wv * 16, 0, lane, 5, 1.f);
  #pragma unroll
  for (int kk = 0; kk < 4; ++kk)
    wP2[kk] = load_wfragT(phase_w2, 128, wv * 16, kk * 32, lane, 128, 1.f);
  #pragma unroll
  for (int kk = 0; kk < 6; ++kk)
    wH1[kk] = load_wfragT(head_w1, 128, wv * 16, kk * 32, lane, 192, 1.f);

  for (int i = tid; i < 128; i += BLKB) S.pb1[i] = phase_b1[i];
  for (int i = tid; i < 128; i += BLKB) S.pb2[i] = phase_b2[i];
  for (int i = tid; i < 128; i += BLKB) S.hw2[i] = head_w2[i];
  for (int i = tid; i < 512; i += BLKB) {
    const int g = i >> 7, c = i & 127;
    float acc = head_b1[c];
    #pragma unroll
    for (int j = 0; j < 8; ++j) acc += region_table[g * 8 + j] * head_w1[(192 + j) * 128 + c];
    S.rbias[g][c] = acc;
  }
  if (tid == 0) { S.consts[0] = head_b2[0]; S.consts[1] = log_std[0]; }
  // stage iteration 0 inputs
  {
    const int n0 = blockIdx.x * ITERB * TLB;
    const int row = tid >> 3, c8 = (tid & 7) * 8;
    *reinterpret_cast<uint4*>(&S.feat[row * 200 + c8]) =
        *reinterpret_cast<const uint4*>(&ctx_in[(size_t)(n0 + row) * 64 + c8]);
    if (tid < 256) {
      const int r = tid >> 2, seg = tid & 3;
      uint4 z = {0, 0, 0, 0};
      if (seg == 0) {
        const float4 p = *reinterpret_cast<const float4*>(&phase_onehot[(n0 + r) * 4]);
        z.x = pack2(p.x, p.y);
        z.y = pack2(p.z, p.w);
        z.z = pack2(elapsed[n0 + r], 0.f);
      }
      *reinterpret_cast<uint4*>(&S.xb[r * 32 + seg * 8]) = z;
    }
    if (tid < 64) {
      int r = region_ids[n0 + tid];
      S.ridx[tid] = r < 0 ? 0 : (r > 3 ? 3 : r);
    }
  }
  __syncthreads();

  for (int it = 0; it < ITERB; ++it) {
    const int n0 = (blockIdx.x * ITERB + it) * TLB;
    const int oc0 = wv * 16 + quad * 4;

    // ---- phase L1 MFMA (K=32 zero-padded), Nt=4 independent chains ----
    {
      f32x4 acc[4] = {Z, Z, Z, Z};
      #pragma unroll
      for (int Nt = 0; Nt < 4; ++Nt)
        acc[Nt] = mfma16(wP1, LDBACT(S.xb, 32, Nt, 0), acc[Nt]);
      const f32x4 bb = *reinterpret_cast<const f32x4*>(&S.pb1[oc0]);
      #pragma unroll
      for (int Nt = 0; Nt < 4; ++Nt) {
        const int row = Nt * 16 + m;
        uint2 u;
        u.x = pack2(fmaxf(acc[Nt][0] + bb[0], 0.f), fmaxf(acc[Nt][1] + bb[1], 0.f));
        u.y = pack2(fmaxf(acc[Nt][2] + bb[2], 0.f), fmaxf(acc[Nt][3] + bb[3], 0.f));
        *reinterpret_cast<uint2*>(&S.ph[row * 136 + oc0]) = u;
      }
    }
    __syncthreads();

    // ---- phase L2 (K=128): pe^T = pw2^T @ ph -> feat cols 64..191 ----
    {
      f32x4 acc[4] = {Z, Z, Z, Z};
      #pragma unroll
      for (int kk = 0; kk < 4; ++kk)
        #pragma unroll
        for (int Nt = 0; Nt < 4; ++Nt)
          acc[Nt] = mfma16(wP2[kk], LDBACT(S.ph, 136, Nt, kk), acc[Nt]);
      const f32x4 bb = *reinterpret_cast<const f32x4*>(&S.pb2[oc0]);
      #pragma unroll
      for (int Nt = 0; Nt < 4; ++Nt) {
        const int row = Nt * 16 + m;
        uint2 u;
        u.x = pack2(fmaxf(acc[Nt][0] + bb[0], 0.f), fmaxf(acc[Nt][1] + bb[1], 0.f));
        u.y = pack2(fmaxf(acc[Nt][2] + bb[2], 0.f), fmaxf(acc[Nt][3] + bb[3], 0.f));
        *reinterpret_cast<uint2*>(&S.feat[row * 200 + 64 + oc0]) = u;
      }
    }
    __syncthreads();

    // ---- head L1 (K=192): hh^T = hw1^T @ feat, per-region bias ----
    {
      f32x4 acc[4] = {Z, Z, Z, Z};
      #pragma unroll
      for (int kk = 0; kk < 6; ++kk)
        #pragma unroll
        for (int Nt = 0; Nt < 4; ++Nt)
          acc[Nt] = mfma16(wH1[kk], LDBACT(S.feat, 200, Nt, kk), acc[Nt]);
      #pragma unroll
      for (int Nt = 0; Nt < 4; ++Nt) {
        const int row = Nt * 16 + m;
        const f32x4 bb = *reinterpret_cast<const f32x4*>(&S.rbias[S.ridx[row]][oc0]);
        uint2 u;
        u.x = pack2(fmaxf(acc[Nt][0] + bb[0], 0.f), fmaxf(acc[Nt][1] + bb[1], 0.f));
        u.y = pack2(fmaxf(acc[Nt][2] + bb[2], 0.f), fmaxf(acc[Nt][3] + bb[3], 0.f));
        *reinterpret_cast<uint2*>(&S.ph[row * 136 + oc0]) = u;   // hh overlay
      }
    }
    __syncthreads();

    // ---- head L2 (128->1) + gaussian; prefetch next iteration's inputs ----
    {
      const int tl = tid >> 3, s = tid & 7;   // 64 TLs x 8 threads
      const unsigned short* hp = &S.ph[tl * 136 + s * 16];
      const bfrag h0 = *reinterpret_cast<const bfrag*>(hp);
      const bfrag h1 = *reinterpret_cast<const bfrag*>(hp + 8);
      float t = 0.f;
      #pragma unroll
      for (int j = 0; j < 8; ++j) {
        t += __uint_as_float(((unsigned int)(unsigned short)h0[j]) << 16) * S.hw2[s * 16 + j];
        t += __uint_as_float(((unsigned int)(unsigned short)h1[j]) << 16) * S.hw2[s * 16 + 8 + j];
      }
      t += __shfl_xor(t, 1);
      t += __shfl_xor(t, 2);
      t += __shfl_xor(t, 4);
      if (s == 0) {
        const int n = n0 + tl;
        const float means = t + S.consts[0];
        const float ls = S.consts[1];
        const float nz = noise[n];
        const float a = means + __expf(ls) * nz;
        out[n] = fminf(fmaxf(a, -1.f), 1.f);
        // (actions - means) == std*noise exactly -> log_prob independent of means
        out[N_TL + n] = -0.5f * (nz * nz + 2.f * ls + 1.8378770664093453f);
      }
      // prefetch next iter (wraps on last; harmless)
      const int nn0 = (blockIdx.x * ITERB + ((it + 1) & (ITERB - 1))) * TLB;
      const int row = tid >> 3, c8 = (tid & 7) * 8;
      *reinterpret_cast<uint4*>(&S.feat[row * 200 + c8]) =
          *reinterpret_cast<const uint4*>(&ctx_in[(size_t)(nn0 + row) * 64 + c8]);
      if (tid < 256) {
        const int r = tid >> 2, seg = tid & 3;
        uint4 z = {0, 0, 0, 0};
        if (seg == 0) {
          const float4 p = *reinterpret_cast<const float4*>(&phase_onehot[(nn0 + r) * 4]);
          z.x = pack2(p.x, p.y);
          z.y = pack2(p.z, p.w);
          z.z = pack2(elapsed[nn0 + r], 0.f);
        }
        *reinterpret_cast<uint4*>(&S.xb[r * 32 + seg * 8]) = z;
      }
      if (tid < 64) {
        int r = region_ids[nn0 + tid];
        S.ridx[tid] = r < 0 ? 0 : (r > 3 ? 3 : r);
      }
    }
    __syncthreads();
  }
}

extern "C" void kernel_launch(void* const* d_in, const int* in_sizes, int n_in,
                              void* d_out, int out_size, void* d_ws, size_t ws_size,
                              hipStream_t stream) {
  const float* queue        = (const float*)d_in[0];
  const float* waiting      = (const float*)d_in[1];
  const float* phase_onehot = (const float*)d_in[2];
  const float* elapsed      = (const float*)d_in[3];
  const int*   region_ids   = (const int*)d_in[4];
  const float* noise        = (const float*)d_in[5];
  const float* lane_w1      = (const float*)d_in[6];
  const float* lane_b1      = (const float*)d_in[7];
  const float* lane_w2      = (const float*)d_in[8];
  const float* lane_b2      = (const float*)d_in[9];
  const float* attn_in_w    = (const float*)d_in[10];
  const float* attn_in_b    = (const float*)d_in[11];
  const float* attn_out_w   = (const float*)d_in[12];
  const float* attn_out_b   = (const float*)d_in[13];
  const float* phase_w1     = (const float*)d_in[14];
  const float* phase_b1     = (const float*)d_in[15];
  const float* phase_w2     = (const float*)d_in[16];
  const float* phase_b2     = (const float*)d_in[17];
  const float* region_table = (const float*)d_in[18];
  const float* head_w1      = (const float*)d_in[19];
  const float* head_b1      = (const float*)d_in[20];
  const float* head_w2      = (const float*)d_in[21];
  const float* head_b2      = (const float*)d_in[22];
  const float* log_std      = (const float*)d_in[23];

  unsigned short* ctx_ws = (unsigned short*)d_ws;   // [N_TL, 64] bf16
  float* out = (float*)d_out;

  hipLaunchKernelGGL(lane_ctx_mfma, dim3(GRID), dim3(BLKA), 0, stream,
                     queue, waiting, elapsed, lane_w1, lane_b1, lane_w2, lane_b2,
                     attn_in_w, attn_in_b, attn_out_w, attn_out_b, ctx_ws);
  hipLaunchKernelGGL(head_mfma, dim3(GRID), dim3(BLKB), 0, stream,
                     phase_onehot, elapsed, region_ids, noise,
                     phase_w1, phase_b1, phase_w2, phase_b2, region_table,
                     head_w1, head_b1, head_w2, head_b2, log_std, ctx_ws, out);
}